// Round 16
// baseline (145.181 us; speedup 1.0000x reference)
//
#include <hip/hip_runtime.h>

#define NTH 256
#define NBOX 16384
#define NCLSIN 91
#define NCLS 90
#define MAXSEL 100
#define TOPK 200
#define TSEL 256      // fallback radix-select size
#define CAP 1024      // candidate slice stride per (b,c): 64 blocks x KSL
#define CANDL 512     // LDS band capacity (batch walk covers <=256)
#define CBCAP 256     // prefetched candidate boxes
#define NBLK 64       // filter blocks per batch (NBOX / BOXPB)
#define BINS 1024
#define GRP 4         // BINS / NTH
#define T0 0.989f     // band threshold: E[C]=180, sigma 13.4; fallbacks guard
#define BOXPB 256     // boxes per filter block
#define KSL 16        // slot capacity per (class, filter-block)

// order-preserving fp32 <-> u32 (strictly monotone for all non-NaN)
__device__ __forceinline__ unsigned fmap(float f) {
    unsigned u = __float_as_uint(f);
    return (u & 0x80000000u) ? ~u : (u | 0x80000000u);
}
__device__ __forceinline__ float funmap(unsigned u) {
    unsigned b = (u & 0x80000000u) ? (u ^ 0x80000000u) : ~u;
    return __uint_as_float(b);
}
__device__ __forceinline__ unsigned long long shfl_xor_u64(unsigned long long v, int mask) {
    unsigned lo = (unsigned)(v & 0xFFFFFFFFull);
    unsigned hi = (unsigned)(v >> 32);
    lo = __shfl_xor(lo, mask, 64);
    hi = __shfl_xor(hi, mask, 64);
    return ((unsigned long long)hi << 32) | (unsigned long long)lo;
}

// Exact reference IoU>0.5 with division-free fast path (r11, verified exact)
__device__ __forceinline__ bool sup_test(float4 s, float sa, float4 c, float ca) {
    float y1 = fmaxf(s.x, c.x);
    float x1 = fmaxf(s.y, c.y);
    float y2 = fminf(s.z, c.z);
    float x2 = fminf(s.w, c.w);
    float dy = fmaxf(__fsub_rn(y2, y1), 0.f);
    float dx = fmaxf(__fsub_rn(x2, x1), 0.f);
    float inter = __fmul_rn(dy, dx);
    float uni = __fsub_rn(__fadd_rn(sa, ca), inter);
    if (!(uni > 0.f)) return false;
    float t = 0.5f * uni;
    if (inter <= t) return false;
    if (inter > __fmul_rn(t, 1.0000005f)) return true;
    return __fdiv_rn(inter, uni) > 0.5f;
}
__device__ __forceinline__ float box_area(float4 b) {
    return __fmul_rn(__fsub_rn(b.z, b.x), __fsub_rn(b.w, b.y));
}

__device__ __forceinline__ void bin_select(unsigned* hist, unsigned* gbuf,
                                           int* sh_g, int* sh_b, unsigned* sh_pb,
                                           int tid, unsigned need) {
    unsigned gs = 0;
#pragma unroll
    for (int q = 0; q < GRP; ++q) gs += hist[tid * GRP + q];
    gbuf[tid] = gs;
    __syncthreads();
    for (int off = 1; off < NTH; off <<= 1) {
        unsigned add = (tid >= off) ? gbuf[tid - off] : 0u;
        __syncthreads();
        gbuf[tid] += add;
        __syncthreads();
    }
    if (tid == 0) *sh_g = NTH - 1;
    __syncthreads();
    if (gbuf[tid] >= need && (tid == 0 || gbuf[tid - 1] < need)) *sh_g = tid;
    __syncthreads();
    if (tid == 0) {
        int g = *sh_g;
        unsigned acc = (g > 0) ? gbuf[g - 1] : 0u;
        int bs = g * GRP + (GRP - 1);
        unsigned pb = acc;
#pragma unroll
        for (int q = 0; q < GRP; ++q) {
            acc += hist[g * GRP + q];
            if (acc >= need) { bs = g * GRP + q; pb = acc; break; }
            pb = acc;
        }
        *sh_b = bs; *sh_pb = pb;
    }
    __syncthreads();
}

// LDS bitonic sort descending (fallback for 256 < C <= CANDL and refill)
__device__ __forceinline__ void sort_desc(unsigned long long* cand, int M, int tid) {
    int P = 1;
    while (P < M) P <<= 1;
    for (int i = M + tid; i < P; i += NTH) cand[i] = 0ull;
    __syncthreads();
    for (int kk = 2; kk <= P; kk <<= 1) {
        for (int jj = kk >> 1; jj > 0; jj >>= 1) {
            for (int i = tid; i < P; i += NTH) {
                int ixj = i ^ jj;
                if (ixj > i) {
                    unsigned long long a = cand[i], c = cand[ixj];
                    bool sw = ((i & kk) == 0) ? (a < c) : (a > c);
                    if (sw) { cand[i] = c; cand[ixj] = a; }
                }
            }
            __syncthreads();
        }
    }
}

// ---------------------------------------------------------------------------
// Kernel 0: stream scores once (4x float4/lane). Hits staged into per-class
// LDS slots; per-(class,block) counts + entries written to this block's OWN
// slice (no global atomics, no pre-zero). Count > KSL -> exact fallback.
// ---------------------------------------------------------------------------
__global__ __launch_bounds__(NTH) void filter_k(const float* __restrict__ in,
                                                unsigned long long* __restrict__ cand_g,
                                                int* __restrict__ cnt2) {
    __shared__ int cnt_s[NCLSIN];
    __shared__ unsigned long long ent[NCLSIN * KSL];

    const int tid = threadIdx.x;
    const int blkid = blockIdx.x;
    const int n0 = blkid * BOXPB;
    const int b = blockIdx.y;
    const int NF4 = BOXPB * NCLSIN / 4;

    for (int i = tid; i < NCLSIN; i += NTH) cnt_s[i] = 0;
    __syncthreads();

    unsigned long long q0 = 0, q1 = 0, q2 = 0, q3 = 0;
    int lc = 0;

    auto emit = [&](unsigned long long pk) {
        unsigned ee = (unsigned)pk;
        int row = (int)ee / NCLSIN;
        int c = (int)ee - row * NCLSIN;
        if (c == 0) return;  // background
        unsigned i = (unsigned)(n0 + row);
        unsigned long long key = (pk & 0xFFFFFFFF00000000ull) | (0xFFFFFFFFu - i);
        int r = atomicAdd(&cnt_s[c], 1);
        if (r < KSL) ent[c * KSL + r] = key;
    };
    auto proc = [&](float4 v, float mx, int idx4) {
        if (mx > T0) {
            const float sv[4] = {v.x, v.y, v.z, v.w};
#pragma unroll
            for (int qq = 0; qq < 4; ++qq) {
                float s = sv[qq];
                if (s > T0) {
                    unsigned long long pk =
                        ((unsigned long long)fmap(s) << 32) |
                        (unsigned)(idx4 * 4 + qq);
                    if (lc == 0) q0 = pk;
                    else if (lc == 1) q1 = pk;
                    else if (lc == 2) q2 = pk;
                    else if (lc == 3) q3 = pk;
                    else emit(pk);
                    ++lc;
                }
            }
        }
    };

    const float4 z4 = make_float4(0.f, 0.f, 0.f, 0.f);
    const float4* src = (const float4*)(in + ((size_t)b * NBOX + n0) * NCLSIN);
    for (int i = tid; i < NF4; i += 4 * NTH) {
        int ib = i + NTH, ic = i + 2 * NTH, id = i + 3 * NTH;
        float4 v1 = src[i];
        float4 v2 = (ib < NF4) ? src[ib] : z4;
        float4 v3 = (ic < NF4) ? src[ic] : z4;
        float4 v4 = (id < NF4) ? src[id] : z4;
        float m1 = fmaxf(fmaxf(v1.x, v1.y), fmaxf(v1.z, v1.w));
        float m2 = fmaxf(fmaxf(v2.x, v2.y), fmaxf(v2.z, v2.w));
        float m3 = fmaxf(fmaxf(v3.x, v3.y), fmaxf(v3.z, v3.w));
        float m4 = fmaxf(fmaxf(v4.x, v4.y), fmaxf(v4.z, v4.w));
        if (fmaxf(fmaxf(m1, m2), fmaxf(m3, m4)) > T0) {
            proc(v1, m1, i);
            proc(v2, m2, ib);
            proc(v3, m3, ic);
            proc(v4, m4, id);
        }
    }
    if (lc > 0) emit(q0);
    if (lc > 1) emit(q1);
    if (lc > 2) emit(q2);
    if (lc > 3) emit(q3);
    __syncthreads();

    if (tid >= 1 && tid < NCLSIN) {
        int c = tid;
        int n = cnt_s[c];
        int bc = b * NCLS + c - 1;
        cnt2[(size_t)bc * NBLK + blkid] = n;
        int lim = n < KSL ? n : KSL;
        for (int j = 0; j < lim; ++j)
            cand_g[(size_t)bc * CAP + blkid * KSL + j] = ent[c * KSL + j];
    }
}

// ---------------------------------------------------------------------------
// Serial greedy walk vs LDS-resident selected list (exact; rare paths only).
// ---------------------------------------------------------------------------
__device__ __forceinline__ void serial_walk_lds(
    const unsigned long long* cand, int from, int to,
    const float4* __restrict__ bbase, const float4* candbox, const float* carea,
    float4* selbox, float* selarea, float* selscore,
    int& nsel, int* sh_nsel, int tid) {
    if (tid < 64) {
        for (int m = from; m < to && nsel < MAXSEL; ++m) {
            unsigned long long key = cand[m];
            float4 bx;
            float ca;
            if (m < CBCAP) { bx = candbox[m]; ca = carea[m]; }
            else { bx = bbase[(int)(0xFFFFFFFFu - (unsigned)key)]; ca = box_area(bx); }
            bool sup = false;
            if (tid < nsel) sup = sup_test(selbox[tid], selarea[tid], bx, ca);
            int l2 = tid + 64;
            if (l2 < nsel) sup = sup || sup_test(selbox[l2], selarea[l2], bx, ca);
            if (!__any(sup)) {
                if (tid == 0) {
                    selbox[nsel] = bx;
                    selarea[nsel] = ca;
                    selscore[nsel] = funmap((unsigned)(key >> 32));
                }
                nsel++;
            }
        }
        if (tid == 0) *sh_nsel = nsel;
    }
    __syncthreads();
    nsel = *sh_nsel;
    __syncthreads();
}

// ---------------------------------------------------------------------------
// Kernel 1: one block per (batch, class). r15 structure, verified exact.
// ---------------------------------------------------------------------------
__global__ __launch_bounds__(NTH) void nms_k(
    const unsigned long long* __restrict__ cand_g,
    const int* __restrict__ cnt2,
    const float* __restrict__ scores_raw,
    const float4* __restrict__ boxes,
    float* __restrict__ ws_sc, float* __restrict__ ws_bx, int use_band) {
    __shared__ unsigned long long cand[CANDL];  // 4 KB
    __shared__ float4 candbox[CBCAP];           // 4 KB (aliased as hist in fallback)
    __shared__ float carea[CBCAP];              // 1 KB
    __shared__ float4 selbox[MAXSEL];           // 1.6 KB
    __shared__ float selarea[MAXSEL];
    __shared__ float selscore[MAXSEL];
    __shared__ unsigned M32[CBCAP * 2];         // 2 KB: 64-bit intra-batch masks
    __shared__ int scnt[NBLK];
    __shared__ int spref[NBLK];
    __shared__ unsigned gbuf[NTH];              // 1 KB
    __shared__ unsigned sh_kmax, sh_pb;
    __shared__ int sh_E, sh_g, sh_b, sh_cnt, sh_nsel, sh_C;
    unsigned* hist = (unsigned*)candbox;  // candbox dead while hist live

    const int tid = threadIdx.x;
    const int c0 = blockIdx.x;
    const int b = blockIdx.y;
    const int bc = b * NCLS + c0;
    const float* sraw = scores_raw + (size_t)b * NBOX * NCLSIN + (c0 + 1);
    const float4* bbase = boxes + (size_t)b * NBOX;

    int nsel = 0;
    unsigned long long lastk = ~0ull;

    int C = 0;
    if (use_band) {
        if (tid < NBLK) scnt[tid] = cnt2[(size_t)bc * NBLK + tid];
        __syncthreads();
        if (tid == 0) {
            int acc = 0;
            bool bad = false;
            for (int k2 = 0; k2 < NBLK; ++k2) {
                spref[k2] = acc;
                int n = scnt[k2];
                if (n > KSL) bad = true;
                acc += n;
            }
            sh_C = bad ? -1 : acc;
        }
        __syncthreads();
        C = sh_C;
        if (C > 0 && C <= CANDL) {
            for (int idx = tid; idx < NBLK * KSL; idx += NTH) {
                int blk = idx >> 4, r = idx & (KSL - 1);
                if (r < scnt[blk])
                    cand[spref[blk] + r] =
                        cand_g[(size_t)bc * CAP + blk * KSL + r];
            }
            __syncthreads();

            if (C <= 256) {
                unsigned long long v = (tid < C) ? cand[tid] : 0ull;
                __syncthreads();
#pragma unroll
                for (int kk = 2; kk <= 256; kk <<= 1) {
#pragma unroll
                    for (int jj = kk >> 1; jj > 0; jj >>= 1) {
                        unsigned long long o;
                        if (jj >= 64) {
                            cand[tid] = v;
                            __syncthreads();
                            o = cand[tid ^ jj];
                            __syncthreads();
                        } else {
                            o = shfl_xor_u64(v, jj);
                        }
                        bool lower = (tid & jj) == 0;
                        bool desc = (tid & kk) == 0;
                        v = (lower == desc) ? (v > o ? v : o) : (v < o ? v : o);
                    }
                }
                cand[tid] = v;
                __syncthreads();

                if (tid < C) {
                    float4 bx = bbase[(int)(0xFFFFFFFFu - (unsigned)cand[tid])];
                    candbox[tid] = bx;
                    carea[tid] = box_area(bx);
                }
                M32[tid] = 0;
                M32[tid + NTH] = 0;
                __syncthreads();

                const int nbatch = (C + 63) >> 6;
                for (int p = tid; p < nbatch * 2016; p += NTH) {
                    int bt = p / 2016;
                    int q = p - bt * 2016;
                    int i = (int)((1.0f + sqrtf(1.0f + 8.0f * (float)q)) * 0.5f);
                    while (i * (i - 1) / 2 > q) --i;
                    while ((i + 1) * i / 2 <= q) ++i;
                    int j = q - i * (i - 1) / 2;
                    int gm = bt * 64 + i, gj = bt * 64 + j;
                    if (gm < C) {
                        if (sup_test(candbox[gj], carea[gj], candbox[gm], carea[gm]))
                            atomicOr(&M32[gm * 2 + (j >> 5)], 1u << (j & 31));
                    }
                }
                __syncthreads();

                if (tid < 64) {
                    for (int bt = 0; bt < nbatch && nsel < MAXSEL; ++bt) {
                        int m = bt * 64 + tid;
                        bool active = m < C;
                        float4 bx = make_float4(0.f, 0.f, 0.f, 0.f);
                        float ca = 0.f;
                        unsigned long long key = 0ull;
                        unsigned long long myM = 0ull;
                        if (active) {
                            key = cand[m];
                            bx = candbox[m];
                            ca = carea[m];
                            myM = ((unsigned long long)M32[m * 2 + 1] << 32) |
                                  M32[m * 2];
                        }
                        bool supV = !active;
                        for (int j = 0; j < nsel; ++j) {
                            if (active)
                                supV = supV || sup_test(selbox[j], selarea[j], bx, ca);
                        }
                        unsigned long long selb = ~__ballot(supV);
                        unsigned long long U = __ballot(myM != 0ull) & selb;
                        while (U) {
                            int mm = __builtin_ctzll(U);
                            U &= U - 1ull;
                            unsigned long long Mm =
                                ((unsigned long long)M32[(bt * 64 + mm) * 2 + 1] << 32) |
                                M32[(bt * 64 + mm) * 2];
                            unsigned long long below =
                                (mm == 0) ? 0ull : ((1ull << mm) - 1ull);
                            if ((selb >> mm) & 1ull) {
                                if (Mm & selb & below) selb &= ~(1ull << mm);
                            }
                        }
                        int avail = MAXSEL - nsel;
                        int pop = __builtin_popcountll(selb);
                        while (pop > avail) {
                            selb &= ~(1ull << (63 - __builtin_clzll(selb)));
                            --pop;
                        }
                        if ((selb >> tid) & 1ull) {
                            unsigned long long below =
                                (tid == 0) ? 0ull : ((1ull << tid) - 1ull);
                            int pos = nsel + __builtin_popcountll(selb & below);
                            selbox[pos] = bx;
                            selarea[pos] = ca;
                            selscore[pos] = funmap((unsigned)(key >> 32));
                        }
                        nsel += pop;
                    }
                    if (tid == 0) sh_nsel = nsel;
                }
                __syncthreads();
                nsel = sh_nsel;
                __syncthreads();
            } else {
                sort_desc(cand, C, tid);
                const int PBX = C < CBCAP ? C : CBCAP;
                for (int i = tid; i < PBX; i += NTH) {
                    float4 bx = bbase[(int)(0xFFFFFFFFu - (unsigned)cand[i])];
                    candbox[i] = bx;
                    carea[i] = box_area(bx);
                }
                __syncthreads();
                serial_walk_lds(cand, 0, C, bbase, candbox, carea,
                                selbox, selarea, selscore, nsel, &sh_nsel, tid);
            }
            lastk = cand[C - 1];
        }
    }

    while (nsel < MAXSEL) {
        unsigned km = 0, ce = 0;
        for (int i = tid; i < NBOX; i += NTH) {
            float s = sraw[(size_t)i * NCLSIN];
            unsigned k = (s > 0.3f) ? fmap(s) : 0u;
            if (k) {
                unsigned long long key =
                    ((unsigned long long)k << 32) | (0xFFFFFFFFu - (unsigned)i);
                if (key < lastk) { ce++; km = km > k ? km : k; }
            }
        }
#pragma unroll
        for (int off = 32; off > 0; off >>= 1) {
            unsigned o = (unsigned)__shfl_xor((int)km, off, 64);
            km = km > o ? km : o;
            ce += (unsigned)__shfl_xor((int)ce, off, 64);
        }
        if ((tid & 63) == 0) { gbuf[tid >> 6] = km; gbuf[8 + (tid >> 6)] = ce; }
        __syncthreads();
        if (tid == 0) {
            unsigned m2 = 0, c2 = 0;
            for (int w = 0; w < NTH / 64; ++w) {
                m2 = m2 > gbuf[w] ? m2 : gbuf[w];
                c2 += gbuf[8 + w];
            }
            sh_kmax = m2; sh_E = (int)c2;
        }
        __syncthreads();
        const int E = sh_E;
        const unsigned kmax = sh_kmax;
        if (E == 0) break;

        unsigned thr = 1u;
        if (E > TSEL) {
            for (int shift = 8;; shift += 4) {
                for (int i = tid; i < BINS; i += NTH) hist[i] = 0u;
                __syncthreads();
                for (int i = tid; i < NBOX; i += NTH) {
                    float s = sraw[(size_t)i * NCLSIN];
                    unsigned k = (s > 0.3f) ? fmap(s) : 0u;
                    if (k) {
                        unsigned long long key =
                            ((unsigned long long)k << 32) | (0xFFFFFFFFu - (unsigned)i);
                        if (key < lastk) {
                            unsigned bin = (kmax - k) >> shift;
                            if (bin < BINS - 1) atomicAdd(&hist[bin], 1u);
                        }
                    }
                }
                __syncthreads();
                bin_select(hist, gbuf, &sh_g, &sh_b, &sh_pb, tid, (unsigned)TSEL);
                if (sh_b < BINS - 1) {
                    long long t = (long long)kmax - ((long long)(sh_b + 1) << shift) + 1;
                    thr = (t < 1) ? 1u : (unsigned)t;
                    break;
                }
            }
        }

        if (tid == 0) sh_cnt = 0;
        __syncthreads();
        for (int i = tid; i < NBOX; i += NTH) {
            float s = sraw[(size_t)i * NCLSIN];
            unsigned k = (s > 0.3f) ? fmap(s) : 0u;
            if (k >= thr) {
                unsigned long long key =
                    ((unsigned long long)k << 32) | (0xFFFFFFFFu - (unsigned)i);
                if (key < lastk) {
                    int pos = atomicAdd(&sh_cnt, 1);
                    if (pos < CANDL) cand[pos] = key;
                }
            }
        }
        __syncthreads();
        const int M = sh_cnt < CANDL ? sh_cnt : CANDL;

        sort_desc(cand, M, tid);
        const int PBX = M < CBCAP ? M : CBCAP;
        for (int i = tid; i < PBX; i += NTH) {
            float4 bx = bbase[(int)(0xFFFFFFFFu - (unsigned)cand[i])];
            candbox[i] = bx;
            carea[i] = box_area(bx);
        }
        __syncthreads();
        serial_walk_lds(cand, 0, M, bbase, candbox, carea,
                        selbox, selarea, selscore, nsel, &sh_nsel, tid);
        if (nsel >= MAXSEL || E <= M) break;
        lastk = cand[M - 1];
        __syncthreads();
    }

    if (tid < MAXSEL) {
        bool v = tid < nsel;
        ws_sc[(size_t)bc * MAXSEL + tid] = v ? selscore[tid] : 0.f;
        ((float4*)ws_bx)[(size_t)bc * MAXSEL + tid] =
            v ? selbox[tid] : make_float4(0.f, 0.f, 0.f, 0.f);
    }
}

// ---------------------------------------------------------------------------
// Kernel 2: one block per batch: stable top-200 of 9000 via radix-select+sort.
// ---------------------------------------------------------------------------
__global__ __launch_bounds__(NTH) void topk_k(const float* __restrict__ ws_sc,
                                              const float* __restrict__ ws_bx,
                                              float* __restrict__ out_sc,
                                              float* __restrict__ out_bx) {
    __shared__ unsigned hist[BINS];
    __shared__ unsigned gbuf[NTH];
    __shared__ unsigned long long cand[CANDL];
    __shared__ unsigned sh_kmax, sh_pb;
    __shared__ int sh_E, sh_g, sh_b, sh_cnt;

    const int tid = threadIdx.x;
    const int b = blockIdx.x;
    const int NF = NCLS * MAXSEL;  // 9000
    const float* sp = ws_sc + (size_t)b * NF;

    unsigned km = 0, ce = 0;
    for (int f = tid; f < NF; f += NTH) {
        unsigned k = __float_as_uint(sp[f]);
        if (k) { ce++; km = km > k ? km : k; }
    }
#pragma unroll
    for (int off = 32; off > 0; off >>= 1) {
        unsigned o = (unsigned)__shfl_xor((int)km, off, 64);
        km = km > o ? km : o;
        ce += (unsigned)__shfl_xor((int)ce, off, 64);
    }
    if ((tid & 63) == 0) { gbuf[tid >> 6] = km; gbuf[8 + (tid >> 6)] = ce; }
    __syncthreads();
    if (tid == 0) {
        unsigned m2 = 0, c2 = 0;
        for (int w = 0; w < NTH / 64; ++w) {
            m2 = m2 > gbuf[w] ? m2 : gbuf[w];
            c2 += gbuf[8 + w];
        }
        sh_kmax = m2; sh_E = (int)c2;
    }
    __syncthreads();
    const int E = sh_E;
    const unsigned kmax = sh_kmax;

    unsigned thr = 1u;
    if (E > TOPK) {
        for (int shift = 8;; shift += 4) {
            for (int i = tid; i < BINS; i += NTH) hist[i] = 0u;
            __syncthreads();
            for (int f = tid; f < NF; f += NTH) {
                unsigned k = __float_as_uint(sp[f]);
                if (k) {
                    unsigned bin = (kmax - k) >> shift;
                    if (bin < BINS - 1) atomicAdd(&hist[bin], 1u);
                }
            }
            __syncthreads();
            bin_select(hist, gbuf, &sh_g, &sh_b, &sh_pb, tid, (unsigned)TOPK);
            if (sh_b < BINS - 1) {
                long long t = (long long)kmax - ((long long)(sh_b + 1) << shift) + 1;
                thr = (t < 1) ? 1u : (unsigned)t;
                break;
            }
        }
    }

    if (tid == 0) sh_cnt = 0;
    __syncthreads();
    for (int f = tid; f < NF; f += NTH) {
        unsigned k = __float_as_uint(sp[f]);
        if (k >= thr) {
            int pos = atomicAdd(&sh_cnt, 1);
            if (pos < CANDL)
                cand[pos] = ((unsigned long long)k << 32) | (0xFFFFFFFFu - (unsigned)f);
        }
    }
    __syncthreads();
    int M = sh_cnt < CANDL ? sh_cnt : CANDL;

    if (M < TOPK) {
        int lim = M + TOPK;
        if (lim > NF) lim = NF;
        for (int f = tid; f < lim; f += NTH) {
            unsigned k = __float_as_uint(sp[f]);
            if (k == 0) {
                int pos = atomicAdd(&sh_cnt, 1);
                if (pos < CANDL)
                    cand[pos] = (unsigned long long)(0xFFFFFFFFu - (unsigned)f);
            }
        }
        __syncthreads();
        M = sh_cnt < CANDL ? sh_cnt : CANDL;
    }

    sort_desc(cand, M, tid);

    for (int k = tid; k < TOPK; k += NTH) {
        float cls = 0.f, s = 0.f;
        float4 bx = make_float4(0.f, 0.f, 0.f, 0.f);
        if (k < M) {
            unsigned long long key = cand[k];
            unsigned f = 0xFFFFFFFFu - (unsigned)key;
            s = __uint_as_float((unsigned)(key >> 32));
            cls = (s > 0.f) ? (float)(f / MAXSEL + 1) : 0.f;
            bx = *(const float4*)(ws_bx + ((size_t)b * NF + f) * 4);
        }
        out_sc[((size_t)b * TOPK + k) * 2 + 0] = cls;
        out_sc[((size_t)b * TOPK + k) * 2 + 1] = s;
        ((float4*)out_bx)[(size_t)b * TOPK + k] = bx;
    }
}

// ---------------------------------------------------------------------------
extern "C" void kernel_launch(void* const* d_in, const int* in_sizes, int n_in,
                              void* d_out, int out_size, void* d_ws, size_t ws_size,
                              hipStream_t stream) {
    const float* scores = (const float*)d_in[0];
    const float4* boxes = (const float4*)d_in[1];
    float* out = (float*)d_out;

    const int B = in_sizes[1] / (NBOX * 4);
    const int NBC = B * NCLS;

    // ws layout: cnt2 [NBC * NBLK ints] | cand [NBC*CAP u64] | sc | bx
    size_t off_cand = ((size_t)NBC * NBLK * 4 + 15) & ~(size_t)15;
    size_t off_sc = off_cand + (size_t)NBC * CAP * 8;
    size_t off_bx = off_sc + (size_t)NBC * MAXSEL * 4;
    size_t need = off_bx + (size_t)NBC * MAXSEL * 16;

    char* ws = (char*)d_ws;
    bool use_band = ws_size >= need;

    int* cnt2;
    unsigned long long* cand_g;
    float *ws_sc, *ws_bx;
    if (use_band) {
        cnt2 = (int*)ws;
        cand_g = (unsigned long long*)(ws + off_cand);
        ws_sc = (float*)(ws + off_sc);
        ws_bx = (float*)(ws + off_bx);
    } else {
        cnt2 = (int*)ws;                   // unused
        cand_g = (unsigned long long*)ws;  // unused
        ws_sc = (float*)ws;
        ws_bx = ws_sc + (size_t)NBC * MAXSEL;
    }

    if (use_band) {
        filter_k<<<dim3(NBOX / BOXPB, B), NTH, 0, stream>>>(scores, cand_g, cnt2);
    }
    // ATTRIBUTION ROUND: nms_k launched TWICE (idempotent: writes a pure
    // function of cand_g/cnt2/scores/boxes). total_r16 - total_r15 = nms_dur.
    nms_k<<<dim3(NCLS, B), NTH, 0, stream>>>(cand_g, cnt2, scores, boxes,
                                             ws_sc, ws_bx, use_band ? 1 : 0);
    nms_k<<<dim3(NCLS, B), NTH, 0, stream>>>(cand_g, cnt2, scores, boxes,
                                             ws_sc, ws_bx, use_band ? 1 : 0);
    topk_k<<<B, NTH, 0, stream>>>(ws_sc, ws_bx, out, out + (size_t)B * TOPK * 2);
}

// Round 17
// 100.062 us; speedup vs baseline: 1.4509x; 1.4509x over previous
//
#include <hip/hip_runtime.h>

#define NTH 256
#define NBOX 16384
#define NCLSIN 91
#define NCLS 90
#define MAXSEL 100
#define TOPK 200
#define TSEL 256      // fallback radix-select size
#define CAP 1024      // candidate slice stride per (b,c): 64 blocks x KSL
#define CANDL 512     // LDS band capacity (batch walk covers <=256)
#define CBCAP 256     // prefetched candidate boxes
#define NBLK 64       // filter blocks per batch (NBOX / BOXPB)
#define BINS 1024
#define GRP 4         // BINS / NTH
#define T0 0.989f     // band threshold: E[C]=180, sigma 13.4; fallbacks guard
#define BOXPB 256     // boxes per filter block
#define KSL 16        // slot capacity per (class, filter-block)

// order-preserving fp32 <-> u32 (strictly monotone for all non-NaN)
__device__ __forceinline__ unsigned fmap(float f) {
    unsigned u = __float_as_uint(f);
    return (u & 0x80000000u) ? ~u : (u | 0x80000000u);
}
__device__ __forceinline__ float funmap(unsigned u) {
    unsigned b = (u & 0x80000000u) ? (u ^ 0x80000000u) : ~u;
    return __uint_as_float(b);
}
__device__ __forceinline__ unsigned long long shfl_xor_u64(unsigned long long v, int mask) {
    unsigned lo = (unsigned)(v & 0xFFFFFFFFull);
    unsigned hi = (unsigned)(v >> 32);
    lo = __shfl_xor(lo, mask, 64);
    hi = __shfl_xor(hi, mask, 64);
    return ((unsigned long long)hi << 32) | (unsigned long long)lo;
}

// Exact reference IoU>0.5 with division-free fast path (r11, verified exact)
__device__ __forceinline__ bool sup_test(float4 s, float sa, float4 c, float ca) {
    float y1 = fmaxf(s.x, c.x);
    float x1 = fmaxf(s.y, c.y);
    float y2 = fminf(s.z, c.z);
    float x2 = fminf(s.w, c.w);
    float dy = fmaxf(__fsub_rn(y2, y1), 0.f);
    float dx = fmaxf(__fsub_rn(x2, x1), 0.f);
    float inter = __fmul_rn(dy, dx);
    float uni = __fsub_rn(__fadd_rn(sa, ca), inter);
    if (!(uni > 0.f)) return false;
    float t = 0.5f * uni;
    if (inter <= t) return false;
    if (inter > __fmul_rn(t, 1.0000005f)) return true;
    return __fdiv_rn(inter, uni) > 0.5f;
}
__device__ __forceinline__ float box_area(float4 b) {
    return __fmul_rn(__fsub_rn(b.z, b.x), __fsub_rn(b.w, b.y));
}

__device__ __forceinline__ void bin_select(unsigned* hist, unsigned* gbuf,
                                           int* sh_g, int* sh_b, unsigned* sh_pb,
                                           int tid, unsigned need) {
    unsigned gs = 0;
#pragma unroll
    for (int q = 0; q < GRP; ++q) gs += hist[tid * GRP + q];
    gbuf[tid] = gs;
    __syncthreads();
    for (int off = 1; off < NTH; off <<= 1) {
        unsigned add = (tid >= off) ? gbuf[tid - off] : 0u;
        __syncthreads();
        gbuf[tid] += add;
        __syncthreads();
    }
    if (tid == 0) *sh_g = NTH - 1;
    __syncthreads();
    if (gbuf[tid] >= need && (tid == 0 || gbuf[tid - 1] < need)) *sh_g = tid;
    __syncthreads();
    if (tid == 0) {
        int g = *sh_g;
        unsigned acc = (g > 0) ? gbuf[g - 1] : 0u;
        int bs = g * GRP + (GRP - 1);
        unsigned pb = acc;
#pragma unroll
        for (int q = 0; q < GRP; ++q) {
            acc += hist[g * GRP + q];
            if (acc >= need) { bs = g * GRP + q; pb = acc; break; }
            pb = acc;
        }
        *sh_b = bs; *sh_pb = pb;
    }
    __syncthreads();
}

// LDS bitonic sort descending (fallback for 256 < C <= CANDL and refill)
__device__ __forceinline__ void sort_desc(unsigned long long* cand, int M, int tid) {
    int P = 1;
    while (P < M) P <<= 1;
    for (int i = M + tid; i < P; i += NTH) cand[i] = 0ull;
    __syncthreads();
    for (int kk = 2; kk <= P; kk <<= 1) {
        for (int jj = kk >> 1; jj > 0; jj >>= 1) {
            for (int i = tid; i < P; i += NTH) {
                int ixj = i ^ jj;
                if (ixj > i) {
                    unsigned long long a = cand[i], c = cand[ixj];
                    bool sw = ((i & kk) == 0) ? (a < c) : (a > c);
                    if (sw) { cand[i] = c; cand[ixj] = a; }
                }
            }
            __syncthreads();
        }
    }
}

// ---------------------------------------------------------------------------
// Kernel 0: stream scores once (4x float4/lane). Hits staged into per-class
// LDS slots; per-(class,block) counts + entries written to this block's OWN
// slice (no global atomics, no pre-zero). Count > KSL -> exact fallback.
// ---------------------------------------------------------------------------
__global__ __launch_bounds__(NTH) void filter_k(const float* __restrict__ in,
                                                unsigned long long* __restrict__ cand_g,
                                                int* __restrict__ cnt2) {
    __shared__ int cnt_s[NCLSIN];
    __shared__ unsigned long long ent[NCLSIN * KSL];

    const int tid = threadIdx.x;
    const int blkid = blockIdx.x;
    const int n0 = blkid * BOXPB;
    const int b = blockIdx.y;
    const int NF4 = BOXPB * NCLSIN / 4;

    for (int i = tid; i < NCLSIN; i += NTH) cnt_s[i] = 0;
    __syncthreads();

    unsigned long long q0 = 0, q1 = 0, q2 = 0, q3 = 0;
    int lc = 0;

    auto emit = [&](unsigned long long pk) {
        unsigned ee = (unsigned)pk;
        int row = (int)ee / NCLSIN;
        int c = (int)ee - row * NCLSIN;
        if (c == 0) return;  // background
        unsigned i = (unsigned)(n0 + row);
        unsigned long long key = (pk & 0xFFFFFFFF00000000ull) | (0xFFFFFFFFu - i);
        int r = atomicAdd(&cnt_s[c], 1);
        if (r < KSL) ent[c * KSL + r] = key;
    };
    auto proc = [&](float4 v, float mx, int idx4) {
        if (mx > T0) {
            const float sv[4] = {v.x, v.y, v.z, v.w};
#pragma unroll
            for (int qq = 0; qq < 4; ++qq) {
                float s = sv[qq];
                if (s > T0) {
                    unsigned long long pk =
                        ((unsigned long long)fmap(s) << 32) |
                        (unsigned)(idx4 * 4 + qq);
                    if (lc == 0) q0 = pk;
                    else if (lc == 1) q1 = pk;
                    else if (lc == 2) q2 = pk;
                    else if (lc == 3) q3 = pk;
                    else emit(pk);
                    ++lc;
                }
            }
        }
    };

    const float4 z4 = make_float4(0.f, 0.f, 0.f, 0.f);
    const float4* src = (const float4*)(in + ((size_t)b * NBOX + n0) * NCLSIN);
    for (int i = tid; i < NF4; i += 4 * NTH) {
        int ib = i + NTH, ic = i + 2 * NTH, id = i + 3 * NTH;
        float4 v1 = src[i];
        float4 v2 = (ib < NF4) ? src[ib] : z4;
        float4 v3 = (ic < NF4) ? src[ic] : z4;
        float4 v4 = (id < NF4) ? src[id] : z4;
        float m1 = fmaxf(fmaxf(v1.x, v1.y), fmaxf(v1.z, v1.w));
        float m2 = fmaxf(fmaxf(v2.x, v2.y), fmaxf(v2.z, v2.w));
        float m3 = fmaxf(fmaxf(v3.x, v3.y), fmaxf(v3.z, v3.w));
        float m4 = fmaxf(fmaxf(v4.x, v4.y), fmaxf(v4.z, v4.w));
        if (fmaxf(fmaxf(m1, m2), fmaxf(m3, m4)) > T0) {
            proc(v1, m1, i);
            proc(v2, m2, ib);
            proc(v3, m3, ic);
            proc(v4, m4, id);
        }
    }
    if (lc > 0) emit(q0);
    if (lc > 1) emit(q1);
    if (lc > 2) emit(q2);
    if (lc > 3) emit(q3);
    __syncthreads();

    if (tid >= 1 && tid < NCLSIN) {
        int c = tid;
        int n = cnt_s[c];
        int bc = b * NCLS + c - 1;
        cnt2[(size_t)bc * NBLK + blkid] = n;
        int lim = n < KSL ? n : KSL;
        for (int j = 0; j < lim; ++j)
            cand_g[(size_t)bc * CAP + blkid * KSL + j] = ent[c * KSL + j];
    }
}

// ---------------------------------------------------------------------------
// Serial greedy walk vs LDS-resident selected list (exact; rare paths only).
// ---------------------------------------------------------------------------
__device__ __forceinline__ void serial_walk_lds(
    const unsigned long long* cand, int from, int to,
    const float4* __restrict__ bbase, const float4* candbox, const float* carea,
    float4* selbox, float* selarea, float* selscore,
    int& nsel, int* sh_nsel, int tid) {
    if (tid < 64) {
        for (int m = from; m < to && nsel < MAXSEL; ++m) {
            unsigned long long key = cand[m];
            float4 bx;
            float ca;
            if (m < CBCAP) { bx = candbox[m]; ca = carea[m]; }
            else { bx = bbase[(int)(0xFFFFFFFFu - (unsigned)key)]; ca = box_area(bx); }
            bool sup = false;
            if (tid < nsel) sup = sup_test(selbox[tid], selarea[tid], bx, ca);
            int l2 = tid + 64;
            if (l2 < nsel) sup = sup || sup_test(selbox[l2], selarea[l2], bx, ca);
            if (!__any(sup)) {
                if (tid == 0) {
                    selbox[nsel] = bx;
                    selarea[nsel] = ca;
                    selscore[nsel] = funmap((unsigned)(key >> 32));
                }
                nsel++;
            }
        }
        if (tid == 0) *sh_nsel = nsel;
    }
    __syncthreads();
    nsel = *sh_nsel;
    __syncthreads();
}

// ---------------------------------------------------------------------------
// Kernel 1: one block per (batch, class). r15 structure with 4-WAVE supV:
// the vs-previously-selected test is split across all 4 waves (stride-4 over
// selections), per-wave ballots OR'd in LDS; wave 0 then runs the verified
// r13 ordered intra-batch resolution + rank-write. Exact.
// ---------------------------------------------------------------------------
__global__ __launch_bounds__(NTH) void nms_k(
    const unsigned long long* __restrict__ cand_g,
    const int* __restrict__ cnt2,
    const float* __restrict__ scores_raw,
    const float4* __restrict__ boxes,
    float* __restrict__ ws_sc, float* __restrict__ ws_bx, int use_band) {
    __shared__ unsigned long long cand[CANDL];  // 4 KB
    __shared__ float4 candbox[CBCAP];           // 4 KB (aliased as hist in fallback)
    __shared__ float carea[CBCAP];              // 1 KB
    __shared__ float4 selbox[MAXSEL];           // 1.6 KB
    __shared__ float selarea[MAXSEL];
    __shared__ float selscore[MAXSEL];
    __shared__ unsigned M32[CBCAP * 2];         // 2 KB: 64-bit intra-batch masks
    __shared__ unsigned long long wballot[4];
    __shared__ int scnt[NBLK];
    __shared__ int spref[NBLK];
    __shared__ unsigned gbuf[NTH];              // 1 KB
    __shared__ unsigned sh_kmax, sh_pb;
    __shared__ int sh_E, sh_g, sh_b, sh_cnt, sh_nsel, sh_C;
    unsigned* hist = (unsigned*)candbox;  // candbox dead while hist live

    const int tid = threadIdx.x;
    const int wv = tid >> 6, ln = tid & 63;
    const int c0 = blockIdx.x;
    const int b = blockIdx.y;
    const int bc = b * NCLS + c0;
    const float* sraw = scores_raw + (size_t)b * NBOX * NCLSIN + (c0 + 1);
    const float4* bbase = boxes + (size_t)b * NBOX;

    int nsel = 0;
    unsigned long long lastk = ~0ull;

    int C = 0;
    if (use_band) {
        if (tid < NBLK) scnt[tid] = cnt2[(size_t)bc * NBLK + tid];
        __syncthreads();
        if (tid == 0) {
            int acc = 0;
            bool bad = false;
            for (int k2 = 0; k2 < NBLK; ++k2) {
                spref[k2] = acc;
                int n = scnt[k2];
                if (n > KSL) bad = true;
                acc += n;
            }
            sh_C = bad ? -1 : acc;
        }
        __syncthreads();
        C = sh_C;
        if (C > 0 && C <= CANDL) {
            for (int idx = tid; idx < NBLK * KSL; idx += NTH) {
                int blk = idx >> 4, r = idx & (KSL - 1);
                if (r < scnt[blk])
                    cand[spref[blk] + r] =
                        cand_g[(size_t)bc * CAP + blk * KSL + r];
            }
            __syncthreads();

            if (C <= 256) {
                // ---- register bitonic sort descending (r12, verified) ----
                unsigned long long v = (tid < C) ? cand[tid] : 0ull;
                __syncthreads();
#pragma unroll
                for (int kk = 2; kk <= 256; kk <<= 1) {
#pragma unroll
                    for (int jj = kk >> 1; jj > 0; jj >>= 1) {
                        unsigned long long o;
                        if (jj >= 64) {
                            cand[tid] = v;
                            __syncthreads();
                            o = cand[tid ^ jj];
                            __syncthreads();
                        } else {
                            o = shfl_xor_u64(v, jj);
                        }
                        bool lower = (tid & jj) == 0;
                        bool desc = (tid & kk) == 0;
                        v = (lower == desc) ? (v > o ? v : o) : (v < o ? v : o);
                    }
                }
                cand[tid] = v;
                __syncthreads();

                if (tid < C) {
                    float4 bx = bbase[(int)(0xFFFFFFFFu - (unsigned)cand[tid])];
                    candbox[tid] = bx;
                    carea[tid] = box_area(bx);
                }
                M32[tid] = 0;
                M32[tid + NTH] = 0;
                __syncthreads();

                // ---- intra-batch matrices (r13): pair q -> (i,j), j<i<64 ----
                const int nbatch = (C + 63) >> 6;
                for (int p = tid; p < nbatch * 2016; p += NTH) {
                    int bt = p / 2016;
                    int q = p - bt * 2016;
                    int i = (int)((1.0f + sqrtf(1.0f + 8.0f * (float)q)) * 0.5f);
                    while (i * (i - 1) / 2 > q) --i;
                    while ((i + 1) * i / 2 <= q) ++i;
                    int j = q - i * (i - 1) / 2;
                    int gm = bt * 64 + i, gj = bt * 64 + j;
                    if (gm < C) {
                        if (sup_test(candbox[gj], carea[gj], candbox[gm], carea[gm]))
                            atomicOr(&M32[gm * 2 + (j >> 5)], 1u << (j & 31));
                    }
                }
                __syncthreads();

                // ---- batch walk: 4-wave supV + wave-0 ordered resolution ----
                for (int bt = 0; bt < nbatch; ++bt) {
                    int m = bt * 64 + ln;
                    bool active = m < C;
                    float4 bx = make_float4(0.f, 0.f, 0.f, 0.f);
                    float ca = 0.f;
                    if (active) { bx = candbox[m]; ca = carea[m]; }
                    // supV split across 4 waves: wave wv tests j = wv, wv+4, ...
                    bool supP = false;
                    if (active) {
                        for (int j = wv; j < nsel; j += 4)
                            supP = supP || sup_test(selbox[j], selarea[j], bx, ca);
                    }
                    unsigned long long bal = __ballot(supP);
                    if (ln == 0) wballot[wv] = bal;
                    __syncthreads();
                    if (tid < 64) {
                        unsigned long long deadSel =
                            wballot[0] | wballot[1] | wballot[2] | wballot[3];
                        unsigned long long actb = __ballot(active);
                        unsigned long long selb = actb & ~deadSel;  // tentative
                        unsigned long long myM = 0ull;
                        if (active)
                            myM = ((unsigned long long)M32[m * 2 + 1] << 32) |
                                  M32[m * 2];
                        unsigned long long U = __ballot(myM != 0ull) & selb;
                        while (U) {
                            int mm = __builtin_ctzll(U);
                            U &= U - 1ull;
                            unsigned long long Mm =
                                ((unsigned long long)M32[(bt * 64 + mm) * 2 + 1] << 32) |
                                M32[(bt * 64 + mm) * 2];
                            unsigned long long below =
                                (mm == 0) ? 0ull : ((1ull << mm) - 1ull);
                            if ((selb >> mm) & 1ull) {
                                if (Mm & selb & below) selb &= ~(1ull << mm);
                            }
                        }
                        int avail = MAXSEL - nsel;
                        int pop = __builtin_popcountll(selb);
                        while (pop > avail) {
                            selb &= ~(1ull << (63 - __builtin_clzll(selb)));
                            --pop;
                        }
                        if ((selb >> ln) & 1ull) {
                            unsigned long long below =
                                (ln == 0) ? 0ull : ((1ull << ln) - 1ull);
                            int pos = nsel + __builtin_popcountll(selb & below);
                            selbox[pos] = bx;
                            selarea[pos] = ca;
                            selscore[pos] = funmap((unsigned)(cand[m] >> 32));
                        }
                        if (ln == 0) sh_nsel = nsel + pop;
                    }
                    __syncthreads();
                    nsel = sh_nsel;
                    if (nsel >= MAXSEL) break;  // uniform (from shared)
                }
                __syncthreads();
            } else {
                sort_desc(cand, C, tid);
                const int PBX = C < CBCAP ? C : CBCAP;
                for (int i = tid; i < PBX; i += NTH) {
                    float4 bx = bbase[(int)(0xFFFFFFFFu - (unsigned)cand[i])];
                    candbox[i] = bx;
                    carea[i] = box_area(bx);
                }
                __syncthreads();
                serial_walk_lds(cand, 0, C, bbase, candbox, carea,
                                selbox, selarea, selscore, nsel, &sh_nsel, tid);
            }
            lastk = cand[C - 1];
        }
    }

    while (nsel < MAXSEL) {
        unsigned km = 0, ce = 0;
        for (int i = tid; i < NBOX; i += NTH) {
            float s = sraw[(size_t)i * NCLSIN];
            unsigned k = (s > 0.3f) ? fmap(s) : 0u;
            if (k) {
                unsigned long long key =
                    ((unsigned long long)k << 32) | (0xFFFFFFFFu - (unsigned)i);
                if (key < lastk) { ce++; km = km > k ? km : k; }
            }
        }
#pragma unroll
        for (int off = 32; off > 0; off >>= 1) {
            unsigned o = (unsigned)__shfl_xor((int)km, off, 64);
            km = km > o ? km : o;
            ce += (unsigned)__shfl_xor((int)ce, off, 64);
        }
        if ((tid & 63) == 0) { gbuf[tid >> 6] = km; gbuf[8 + (tid >> 6)] = ce; }
        __syncthreads();
        if (tid == 0) {
            unsigned m2 = 0, c2 = 0;
            for (int w = 0; w < NTH / 64; ++w) {
                m2 = m2 > gbuf[w] ? m2 : gbuf[w];
                c2 += gbuf[8 + w];
            }
            sh_kmax = m2; sh_E = (int)c2;
        }
        __syncthreads();
        const int E = sh_E;
        const unsigned kmax = sh_kmax;
        if (E == 0) break;

        unsigned thr = 1u;
        if (E > TSEL) {
            for (int shift = 8;; shift += 4) {
                for (int i = tid; i < BINS; i += NTH) hist[i] = 0u;
                __syncthreads();
                for (int i = tid; i < NBOX; i += NTH) {
                    float s = sraw[(size_t)i * NCLSIN];
                    unsigned k = (s > 0.3f) ? fmap(s) : 0u;
                    if (k) {
                        unsigned long long key =
                            ((unsigned long long)k << 32) | (0xFFFFFFFFu - (unsigned)i);
                        if (key < lastk) {
                            unsigned bin = (kmax - k) >> shift;
                            if (bin < BINS - 1) atomicAdd(&hist[bin], 1u);
                        }
                    }
                }
                __syncthreads();
                bin_select(hist, gbuf, &sh_g, &sh_b, &sh_pb, tid, (unsigned)TSEL);
                if (sh_b < BINS - 1) {
                    long long t = (long long)kmax - ((long long)(sh_b + 1) << shift) + 1;
                    thr = (t < 1) ? 1u : (unsigned)t;
                    break;
                }
            }
        }

        if (tid == 0) sh_cnt = 0;
        __syncthreads();
        for (int i = tid; i < NBOX; i += NTH) {
            float s = sraw[(size_t)i * NCLSIN];
            unsigned k = (s > 0.3f) ? fmap(s) : 0u;
            if (k >= thr) {
                unsigned long long key =
                    ((unsigned long long)k << 32) | (0xFFFFFFFFu - (unsigned)i);
                if (key < lastk) {
                    int pos = atomicAdd(&sh_cnt, 1);
                    if (pos < CANDL) cand[pos] = key;
                }
            }
        }
        __syncthreads();
        const int M = sh_cnt < CANDL ? sh_cnt : CANDL;

        sort_desc(cand, M, tid);
        const int PBX = M < CBCAP ? M : CBCAP;
        for (int i = tid; i < PBX; i += NTH) {
            float4 bx = bbase[(int)(0xFFFFFFFFu - (unsigned)cand[i])];
            candbox[i] = bx;
            carea[i] = box_area(bx);
        }
        __syncthreads();
        serial_walk_lds(cand, 0, M, bbase, candbox, carea,
                        selbox, selarea, selscore, nsel, &sh_nsel, tid);
        if (nsel >= MAXSEL || E <= M) break;
        lastk = cand[M - 1];
        __syncthreads();
    }

    if (tid < MAXSEL) {
        bool v = tid < nsel;
        ws_sc[(size_t)bc * MAXSEL + tid] = v ? selscore[tid] : 0.f;
        ((float4*)ws_bx)[(size_t)bc * MAXSEL + tid] =
            v ? selbox[tid] : make_float4(0.f, 0.f, 0.f, 0.f);
    }
}

// ---------------------------------------------------------------------------
// Kernel 2: one block per batch: stable top-200 of 9000 via radix-select+sort.
// ---------------------------------------------------------------------------
__global__ __launch_bounds__(NTH) void topk_k(const float* __restrict__ ws_sc,
                                              const float* __restrict__ ws_bx,
                                              float* __restrict__ out_sc,
                                              float* __restrict__ out_bx) {
    __shared__ unsigned hist[BINS];
    __shared__ unsigned gbuf[NTH];
    __shared__ unsigned long long cand[CANDL];
    __shared__ unsigned sh_kmax, sh_pb;
    __shared__ int sh_E, sh_g, sh_b, sh_cnt;

    const int tid = threadIdx.x;
    const int b = blockIdx.x;
    const int NF = NCLS * MAXSEL;  // 9000
    const float* sp = ws_sc + (size_t)b * NF;

    unsigned km = 0, ce = 0;
    for (int f = tid; f < NF; f += NTH) {
        unsigned k = __float_as_uint(sp[f]);
        if (k) { ce++; km = km > k ? km : k; }
    }
#pragma unroll
    for (int off = 32; off > 0; off >>= 1) {
        unsigned o = (unsigned)__shfl_xor((int)km, off, 64);
        km = km > o ? km : o;
        ce += (unsigned)__shfl_xor((int)ce, off, 64);
    }
    if ((tid & 63) == 0) { gbuf[tid >> 6] = km; gbuf[8 + (tid >> 6)] = ce; }
    __syncthreads();
    if (tid == 0) {
        unsigned m2 = 0, c2 = 0;
        for (int w = 0; w < NTH / 64; ++w) {
            m2 = m2 > gbuf[w] ? m2 : gbuf[w];
            c2 += gbuf[8 + w];
        }
        sh_kmax = m2; sh_E = (int)c2;
    }
    __syncthreads();
    const int E = sh_E;
    const unsigned kmax = sh_kmax;

    unsigned thr = 1u;
    if (E > TOPK) {
        for (int shift = 8;; shift += 4) {
            for (int i = tid; i < BINS; i += NTH) hist[i] = 0u;
            __syncthreads();
            for (int f = tid; f < NF; f += NTH) {
                unsigned k = __float_as_uint(sp[f]);
                if (k) {
                    unsigned bin = (kmax - k) >> shift;
                    if (bin < BINS - 1) atomicAdd(&hist[bin], 1u);
                }
            }
            __syncthreads();
            bin_select(hist, gbuf, &sh_g, &sh_b, &sh_pb, tid, (unsigned)TOPK);
            if (sh_b < BINS - 1) {
                long long t = (long long)kmax - ((long long)(sh_b + 1) << shift) + 1;
                thr = (t < 1) ? 1u : (unsigned)t;
                break;
            }
        }
    }

    if (tid == 0) sh_cnt = 0;
    __syncthreads();
    for (int f = tid; f < NF; f += NTH) {
        unsigned k = __float_as_uint(sp[f]);
        if (k >= thr) {
            int pos = atomicAdd(&sh_cnt, 1);
            if (pos < CANDL)
                cand[pos] = ((unsigned long long)k << 32) | (0xFFFFFFFFu - (unsigned)f);
        }
    }
    __syncthreads();
    int M = sh_cnt < CANDL ? sh_cnt : CANDL;

    if (M < TOPK) {
        int lim = M + TOPK;
        if (lim > NF) lim = NF;
        for (int f = tid; f < lim; f += NTH) {
            unsigned k = __float_as_uint(sp[f]);
            if (k == 0) {
                int pos = atomicAdd(&sh_cnt, 1);
                if (pos < CANDL)
                    cand[pos] = (unsigned long long)(0xFFFFFFFFu - (unsigned)f);
            }
        }
        __syncthreads();
        M = sh_cnt < CANDL ? sh_cnt : CANDL;
    }

    sort_desc(cand, M, tid);

    for (int k = tid; k < TOPK; k += NTH) {
        float cls = 0.f, s = 0.f;
        float4 bx = make_float4(0.f, 0.f, 0.f, 0.f);
        if (k < M) {
            unsigned long long key = cand[k];
            unsigned f = 0xFFFFFFFFu - (unsigned)key;
            s = __uint_as_float((unsigned)(key >> 32));
            cls = (s > 0.f) ? (float)(f / MAXSEL + 1) : 0.f;
            bx = *(const float4*)(ws_bx + ((size_t)b * NF + f) * 4);
        }
        out_sc[((size_t)b * TOPK + k) * 2 + 0] = cls;
        out_sc[((size_t)b * TOPK + k) * 2 + 1] = s;
        ((float4*)out_bx)[(size_t)b * TOPK + k] = bx;
    }
}

// ---------------------------------------------------------------------------
extern "C" void kernel_launch(void* const* d_in, const int* in_sizes, int n_in,
                              void* d_out, int out_size, void* d_ws, size_t ws_size,
                              hipStream_t stream) {
    const float* scores = (const float*)d_in[0];
    const float4* boxes = (const float4*)d_in[1];
    float* out = (float*)d_out;

    const int B = in_sizes[1] / (NBOX * 4);
    const int NBC = B * NCLS;

    // ws layout: cnt2 [NBC * NBLK ints] | cand [NBC*CAP u64] | sc | bx
    size_t off_cand = ((size_t)NBC * NBLK * 4 + 15) & ~(size_t)15;
    size_t off_sc = off_cand + (size_t)NBC * CAP * 8;
    size_t off_bx = off_sc + (size_t)NBC * MAXSEL * 4;
    size_t need = off_bx + (size_t)NBC * MAXSEL * 16;

    char* ws = (char*)d_ws;
    bool use_band = ws_size >= need;

    int* cnt2;
    unsigned long long* cand_g;
    float *ws_sc, *ws_bx;
    if (use_band) {
        cnt2 = (int*)ws;
        cand_g = (unsigned long long*)(ws + off_cand);
        ws_sc = (float*)(ws + off_sc);
        ws_bx = (float*)(ws + off_bx);
    } else {
        cnt2 = (int*)ws;                   // unused
        cand_g = (unsigned long long*)ws;  // unused
        ws_sc = (float*)ws;
        ws_bx = ws_sc + (size_t)NBC * MAXSEL;
    }

    if (use_band) {
        filter_k<<<dim3(NBOX / BOXPB, B), NTH, 0, stream>>>(scores, cand_g, cnt2);
    }
    nms_k<<<dim3(NCLS, B), NTH, 0, stream>>>(cand_g, cnt2, scores, boxes,
                                             ws_sc, ws_bx, use_band ? 1 : 0);
    topk_k<<<B, NTH, 0, stream>>>(ws_sc, ws_bx, out, out + (size_t)B * TOPK * 2);
}

// Round 19
// 94.676 us; speedup vs baseline: 1.5335x; 1.0569x over previous
//
#include <hip/hip_runtime.h>

#define NTH 256
#define NBOX 16384
#define NCLSIN 91
#define NCLS 90
#define MAXSEL 100
#define TOPK 200
#define TSEL 256      // fallback radix-select size
#define CAP 1024      // candidate slice stride per (b,c): 64 blocks x KSL
#define CANDL 512     // LDS band capacity (batch walk covers <=256)
#define CBCAP 256     // prefetched candidate boxes
#define NBLK 64       // filter blocks per batch (NBOX / BOXPB)
#define BINS 1024
#define GRP 4         // BINS / NTH
#define T0 0.989f     // band threshold: E[C]=180, sigma 13.4; fallbacks guard
#define BOXPB 256     // boxes per filter block
#define KSL 16        // slot capacity per (class, filter-block)

// order-preserving fp32 <-> u32 (strictly monotone for all non-NaN)
__device__ __forceinline__ unsigned fmap(float f) {
    unsigned u = __float_as_uint(f);
    return (u & 0x80000000u) ? ~u : (u | 0x80000000u);
}
__device__ __forceinline__ float funmap(unsigned u) {
    unsigned b = (u & 0x80000000u) ? (u ^ 0x80000000u) : ~u;
    return __uint_as_float(b);
}
__device__ __forceinline__ unsigned long long shfl_xor_u64(unsigned long long v, int mask) {
    unsigned lo = (unsigned)(v & 0xFFFFFFFFull);
    unsigned hi = (unsigned)(v >> 32);
    lo = __shfl_xor(lo, mask, 64);
    hi = __shfl_xor(hi, mask, 64);
    return ((unsigned long long)hi << 32) | (unsigned long long)lo;
}

// Exact reference IoU>0.5 with division-free fast path (r11, verified exact)
__device__ __forceinline__ bool sup_test(float4 s, float sa, float4 c, float ca) {
    float y1 = fmaxf(s.x, c.x);
    float x1 = fmaxf(s.y, c.y);
    float y2 = fminf(s.z, c.z);
    float x2 = fminf(s.w, c.w);
    float dy = fmaxf(__fsub_rn(y2, y1), 0.f);
    float dx = fmaxf(__fsub_rn(x2, x1), 0.f);
    float inter = __fmul_rn(dy, dx);
    float uni = __fsub_rn(__fadd_rn(sa, ca), inter);
    if (!(uni > 0.f)) return false;
    float t = 0.5f * uni;
    if (inter <= t) return false;
    if (inter > __fmul_rn(t, 1.0000005f)) return true;
    return __fdiv_rn(inter, uni) > 0.5f;
}
__device__ __forceinline__ float box_area(float4 b) {
    return __fmul_rn(__fsub_rn(b.z, b.x), __fsub_rn(b.w, b.y));
}

__device__ __forceinline__ void bin_select(unsigned* hist, unsigned* gbuf,
                                           int* sh_g, int* sh_b, unsigned* sh_pb,
                                           int tid, unsigned need) {
    unsigned gs = 0;
#pragma unroll
    for (int q = 0; q < GRP; ++q) gs += hist[tid * GRP + q];
    gbuf[tid] = gs;
    __syncthreads();
    for (int off = 1; off < NTH; off <<= 1) {
        unsigned add = (tid >= off) ? gbuf[tid - off] : 0u;
        __syncthreads();
        gbuf[tid] += add;
        __syncthreads();
    }
    if (tid == 0) *sh_g = NTH - 1;
    __syncthreads();
    if (gbuf[tid] >= need && (tid == 0 || gbuf[tid - 1] < need)) *sh_g = tid;
    __syncthreads();
    if (tid == 0) {
        int g = *sh_g;
        unsigned acc = (g > 0) ? gbuf[g - 1] : 0u;
        int bs = g * GRP + (GRP - 1);
        unsigned pb = acc;
#pragma unroll
        for (int q = 0; q < GRP; ++q) {
            acc += hist[g * GRP + q];
            if (acc >= need) { bs = g * GRP + q; pb = acc; break; }
            pb = acc;
        }
        *sh_b = bs; *sh_pb = pb;
    }
    __syncthreads();
}

// LDS bitonic sort descending (fallback for 256 < C <= CANDL and refill)
__device__ __forceinline__ void sort_desc(unsigned long long* cand, int M, int tid) {
    int P = 1;
    while (P < M) P <<= 1;
    for (int i = M + tid; i < P; i += NTH) cand[i] = 0ull;
    __syncthreads();
    for (int kk = 2; kk <= P; kk <<= 1) {
        for (int jj = kk >> 1; jj > 0; jj >>= 1) {
            for (int i = tid; i < P; i += NTH) {
                int ixj = i ^ jj;
                if (ixj > i) {
                    unsigned long long a = cand[i], c = cand[ixj];
                    bool sw = ((i & kk) == 0) ? (a < c) : (a > c);
                    if (sw) { cand[i] = c; cand[ixj] = a; }
                }
            }
            __syncthreads();
        }
    }
}

// ---------------------------------------------------------------------------
// Kernel 0: stream scores once (4x float4/lane). Hits staged into per-class
// LDS slots; per-(class,block) counts + entries written to this block's OWN
// slice (no global atomics, no pre-zero). Count > KSL -> exact fallback.
// ---------------------------------------------------------------------------
__global__ __launch_bounds__(NTH) void filter_k(const float* __restrict__ in,
                                                unsigned long long* __restrict__ cand_g,
                                                int* __restrict__ cnt2) {
    __shared__ int cnt_s[NCLSIN];
    __shared__ unsigned long long ent[NCLSIN * KSL];

    const int tid = threadIdx.x;
    const int blkid = blockIdx.x;
    const int n0 = blkid * BOXPB;
    const int b = blockIdx.y;
    const int NF4 = BOXPB * NCLSIN / 4;

    for (int i = tid; i < NCLSIN; i += NTH) cnt_s[i] = 0;
    __syncthreads();

    unsigned long long q0 = 0, q1 = 0, q2 = 0, q3 = 0;
    int lc = 0;

    auto emit = [&](unsigned long long pk) {
        unsigned ee = (unsigned)pk;
        int row = (int)ee / NCLSIN;
        int c = (int)ee - row * NCLSIN;
        if (c == 0) return;  // background
        unsigned i = (unsigned)(n0 + row);
        unsigned long long key = (pk & 0xFFFFFFFF00000000ull) | (0xFFFFFFFFu - i);
        int r = atomicAdd(&cnt_s[c], 1);
        if (r < KSL) ent[c * KSL + r] = key;
    };
    auto proc = [&](float4 v, float mx, int idx4) {
        if (mx > T0) {
            const float sv[4] = {v.x, v.y, v.z, v.w};
#pragma unroll
            for (int qq = 0; qq < 4; ++qq) {
                float s = sv[qq];
                if (s > T0) {
                    unsigned long long pk =
                        ((unsigned long long)fmap(s) << 32) |
                        (unsigned)(idx4 * 4 + qq);
                    if (lc == 0) q0 = pk;
                    else if (lc == 1) q1 = pk;
                    else if (lc == 2) q2 = pk;
                    else if (lc == 3) q3 = pk;
                    else emit(pk);
                    ++lc;
                }
            }
        }
    };

    const float4 z4 = make_float4(0.f, 0.f, 0.f, 0.f);
    const float4* src = (const float4*)(in + ((size_t)b * NBOX + n0) * NCLSIN);
    for (int i = tid; i < NF4; i += 4 * NTH) {
        int ib = i + NTH, ic = i + 2 * NTH, id = i + 3 * NTH;
        float4 v1 = src[i];
        float4 v2 = (ib < NF4) ? src[ib] : z4;
        float4 v3 = (ic < NF4) ? src[ic] : z4;
        float4 v4 = (id < NF4) ? src[id] : z4;
        float m1 = fmaxf(fmaxf(v1.x, v1.y), fmaxf(v1.z, v1.w));
        float m2 = fmaxf(fmaxf(v2.x, v2.y), fmaxf(v2.z, v2.w));
        float m3 = fmaxf(fmaxf(v3.x, v3.y), fmaxf(v3.z, v3.w));
        float m4 = fmaxf(fmaxf(v4.x, v4.y), fmaxf(v4.z, v4.w));
        if (fmaxf(fmaxf(m1, m2), fmaxf(m3, m4)) > T0) {
            proc(v1, m1, i);
            proc(v2, m2, ib);
            proc(v3, m3, ic);
            proc(v4, m4, id);
        }
    }
    if (lc > 0) emit(q0);
    if (lc > 1) emit(q1);
    if (lc > 2) emit(q2);
    if (lc > 3) emit(q3);
    __syncthreads();

    if (tid >= 1 && tid < NCLSIN) {
        int c = tid;
        int n = cnt_s[c];
        int bc = b * NCLS + c - 1;
        cnt2[(size_t)bc * NBLK + blkid] = n;
        int lim = n < KSL ? n : KSL;
        for (int j = 0; j < lim; ++j)
            cand_g[(size_t)bc * CAP + blkid * KSL + j] = ent[c * KSL + j];
    }
}

// ---------------------------------------------------------------------------
// Serial greedy walk vs LDS-resident selected list (exact; rare paths only).
// ---------------------------------------------------------------------------
__device__ __forceinline__ void serial_walk_lds(
    const unsigned long long* cand, int from, int to,
    const float4* __restrict__ bbase, const float4* candbox, const float* carea,
    float4* selbox, float* selarea, float* selscore,
    int& nsel, int* sh_nsel, int tid) {
    if (tid < 64) {
        for (int m = from; m < to && nsel < MAXSEL; ++m) {
            unsigned long long key = cand[m];
            float4 bx;
            float ca;
            if (m < CBCAP) { bx = candbox[m]; ca = carea[m]; }
            else { bx = bbase[(int)(0xFFFFFFFFu - (unsigned)key)]; ca = box_area(bx); }
            bool sup = false;
            if (tid < nsel) sup = sup_test(selbox[tid], selarea[tid], bx, ca);
            int l2 = tid + 64;
            if (l2 < nsel) sup = sup || sup_test(selbox[l2], selarea[l2], bx, ca);
            if (!__any(sup)) {
                if (tid == 0) {
                    selbox[nsel] = bx;
                    selarea[nsel] = ca;
                    selscore[nsel] = funmap((unsigned)(key >> 32));
                }
                nsel++;
            }
        }
        if (tid == 0) *sh_nsel = nsel;
    }
    __syncthreads();
    nsel = *sh_nsel;
    __syncthreads();
}

// ---------------------------------------------------------------------------
// Kernel 1: one block per (batch, class). r17 structure (4-wave supV) with
// wave-parallel shfl prefix scan replacing the serial count prefix. Exact.
// ---------------------------------------------------------------------------
__global__ __launch_bounds__(NTH) void nms_k(
    const unsigned long long* __restrict__ cand_g,
    const int* __restrict__ cnt2,
    const float* __restrict__ scores_raw,
    const float4* __restrict__ boxes,
    float* __restrict__ ws_sc, float* __restrict__ ws_bx, int use_band) {
    __shared__ unsigned long long cand[CANDL];  // 4 KB
    __shared__ float4 candbox[CBCAP];           // 4 KB (aliased as hist in fallback)
    __shared__ float carea[CBCAP];              // 1 KB
    __shared__ float4 selbox[MAXSEL];           // 1.6 KB
    __shared__ float selarea[MAXSEL];
    __shared__ float selscore[MAXSEL];
    __shared__ unsigned M32[CBCAP * 2];         // 2 KB: 64-bit intra-batch masks
    __shared__ unsigned long long wballot[4];
    __shared__ int scnt[NBLK];
    __shared__ int spref[NBLK];
    __shared__ unsigned gbuf[NTH];              // 1 KB
    __shared__ unsigned sh_kmax, sh_pb;
    __shared__ int sh_E, sh_g, sh_b, sh_cnt, sh_nsel, sh_C;
    unsigned* hist = (unsigned*)candbox;  // candbox dead while hist live

    const int tid = threadIdx.x;
    const int wv = tid >> 6, ln = tid & 63;
    const int c0 = blockIdx.x;
    const int b = blockIdx.y;
    const int bc = b * NCLS + c0;
    const float* sraw = scores_raw + (size_t)b * NBOX * NCLSIN + (c0 + 1);
    const float4* bbase = boxes + (size_t)b * NBOX;

    int nsel = 0;
    unsigned long long lastk = ~0ull;

    int C = 0;
    if (use_band) {
        // ---- wave-0 parallel prefix over 64 slot counts ----
        if (tid < 64) {
            int n = cnt2[(size_t)bc * NBLK + tid];
            scnt[tid] = n;
            int x = n;
#pragma unroll
            for (int off = 1; off < 64; off <<= 1) {
                int y = __shfl_up(x, off, 64);
                if (tid >= off) x += y;
            }
            spref[tid] = x - n;  // exclusive prefix
            unsigned long long bb = __ballot(n > KSL);
            if (tid == 63) sh_C = (bb != 0ull) ? -1 : x;  // x@63 = total
        }
        __syncthreads();
        C = sh_C;
        if (C > 0 && C <= CANDL) {
            for (int idx = tid; idx < NBLK * KSL; idx += NTH) {
                int blk = idx >> 4, r = idx & (KSL - 1);
                if (r < scnt[blk])
                    cand[spref[blk] + r] =
                        cand_g[(size_t)bc * CAP + blk * KSL + r];
            }
            __syncthreads();

            if (C <= 256) {
                // ---- register bitonic sort descending (r12, verified) ----
                unsigned long long v = (tid < C) ? cand[tid] : 0ull;
                __syncthreads();
#pragma unroll
                for (int kk = 2; kk <= 256; kk <<= 1) {
#pragma unroll
                    for (int jj = kk >> 1; jj > 0; jj >>= 1) {
                        unsigned long long o;
                        if (jj >= 64) {
                            cand[tid] = v;
                            __syncthreads();
                            o = cand[tid ^ jj];
                            __syncthreads();
                        } else {
                            o = shfl_xor_u64(v, jj);
                        }
                        bool lower = (tid & jj) == 0;
                        bool desc = (tid & kk) == 0;
                        v = (lower == desc) ? (v > o ? v : o) : (v < o ? v : o);
                    }
                }
                cand[tid] = v;
                __syncthreads();

                if (tid < C) {
                    float4 bx = bbase[(int)(0xFFFFFFFFu - (unsigned)cand[tid])];
                    candbox[tid] = bx;
                    carea[tid] = box_area(bx);
                }
                M32[tid] = 0;
                M32[tid + NTH] = 0;
                __syncthreads();

                // ---- intra-batch matrices (r13): pair q -> (i,j), j<i<64 ----
                const int nbatch = (C + 63) >> 6;
                for (int p = tid; p < nbatch * 2016; p += NTH) {
                    int bt = p / 2016;
                    int q = p - bt * 2016;
                    int i = (int)((1.0f + sqrtf(1.0f + 8.0f * (float)q)) * 0.5f);
                    while (i * (i - 1) / 2 > q) --i;
                    while ((i + 1) * i / 2 <= q) ++i;
                    int j = q - i * (i - 1) / 2;
                    int gm = bt * 64 + i, gj = bt * 64 + j;
                    if (gm < C) {
                        if (sup_test(candbox[gj], carea[gj], candbox[gm], carea[gm]))
                            atomicOr(&M32[gm * 2 + (j >> 5)], 1u << (j & 31));
                    }
                }
                __syncthreads();

                // ---- batch walk: 4-wave supV + wave-0 ordered resolution ----
                for (int bt = 0; bt < nbatch; ++bt) {
                    int m = bt * 64 + ln;
                    bool active = m < C;
                    float4 bx = make_float4(0.f, 0.f, 0.f, 0.f);
                    float ca = 0.f;
                    if (active) { bx = candbox[m]; ca = carea[m]; }
                    bool supP = false;
                    if (active) {
                        for (int j = wv; j < nsel; j += 4)
                            supP = supP || sup_test(selbox[j], selarea[j], bx, ca);
                    }
                    unsigned long long bal = __ballot(supP);
                    if (ln == 0) wballot[wv] = bal;
                    __syncthreads();
                    if (tid < 64) {
                        unsigned long long deadSel =
                            wballot[0] | wballot[1] | wballot[2] | wballot[3];
                        unsigned long long actb = __ballot(active);
                        unsigned long long selb = actb & ~deadSel;  // tentative
                        unsigned long long myM = 0ull;
                        if (active)
                            myM = ((unsigned long long)M32[m * 2 + 1] << 32) |
                                  M32[m * 2];
                        unsigned long long U = __ballot(myM != 0ull) & selb;
                        while (U) {
                            int mm = __builtin_ctzll(U);
                            U &= U - 1ull;
                            unsigned long long Mm =
                                ((unsigned long long)M32[(bt * 64 + mm) * 2 + 1] << 32) |
                                M32[(bt * 64 + mm) * 2];
                            unsigned long long below =
                                (mm == 0) ? 0ull : ((1ull << mm) - 1ull);
                            if ((selb >> mm) & 1ull) {
                                if (Mm & selb & below) selb &= ~(1ull << mm);
                            }
                        }
                        int avail = MAXSEL - nsel;
                        int pop = __builtin_popcountll(selb);
                        while (pop > avail) {
                            selb &= ~(1ull << (63 - __builtin_clzll(selb)));
                            --pop;
                        }
                        if ((selb >> ln) & 1ull) {
                            unsigned long long below =
                                (ln == 0) ? 0ull : ((1ull << ln) - 1ull);
                            int pos = nsel + __builtin_popcountll(selb & below);
                            selbox[pos] = bx;
                            selarea[pos] = ca;
                            selscore[pos] = funmap((unsigned)(cand[m] >> 32));
                        }
                        if (ln == 0) sh_nsel = nsel + pop;
                    }
                    __syncthreads();
                    nsel = sh_nsel;
                    if (nsel >= MAXSEL) break;  // uniform (from shared)
                }
                __syncthreads();
            } else {
                sort_desc(cand, C, tid);
                const int PBX = C < CBCAP ? C : CBCAP;
                for (int i = tid; i < PBX; i += NTH) {
                    float4 bx = bbase[(int)(0xFFFFFFFFu - (unsigned)cand[i])];
                    candbox[i] = bx;
                    carea[i] = box_area(bx);
                }
                __syncthreads();
                serial_walk_lds(cand, 0, C, bbase, candbox, carea,
                                selbox, selarea, selscore, nsel, &sh_nsel, tid);
            }
            lastk = cand[C - 1];
        }
    }

    while (nsel < MAXSEL) {
        unsigned km = 0, ce = 0;
        for (int i = tid; i < NBOX; i += NTH) {
            float s = sraw[(size_t)i * NCLSIN];
            unsigned k = (s > 0.3f) ? fmap(s) : 0u;
            if (k) {
                unsigned long long key =
                    ((unsigned long long)k << 32) | (0xFFFFFFFFu - (unsigned)i);
                if (key < lastk) { ce++; km = km > k ? km : k; }
            }
        }
#pragma unroll
        for (int off = 32; off > 0; off >>= 1) {
            unsigned o = (unsigned)__shfl_xor((int)km, off, 64);
            km = km > o ? km : o;
            ce += (unsigned)__shfl_xor((int)ce, off, 64);
        }
        if ((tid & 63) == 0) { gbuf[tid >> 6] = km; gbuf[8 + (tid >> 6)] = ce; }
        __syncthreads();
        if (tid == 0) {
            unsigned m2 = 0, c2 = 0;
            for (int w = 0; w < NTH / 64; ++w) {
                m2 = m2 > gbuf[w] ? m2 : gbuf[w];
                c2 += gbuf[8 + w];
            }
            sh_kmax = m2; sh_E = (int)c2;
        }
        __syncthreads();
        const int E = sh_E;
        const unsigned kmax = sh_kmax;
        if (E == 0) break;

        unsigned thr = 1u;
        if (E > TSEL) {
            for (int shift = 8;; shift += 4) {
                for (int i = tid; i < BINS; i += NTH) hist[i] = 0u;
                __syncthreads();
                for (int i = tid; i < NBOX; i += NTH) {
                    float s = sraw[(size_t)i * NCLSIN];
                    unsigned k = (s > 0.3f) ? fmap(s) : 0u;
                    if (k) {
                        unsigned long long key =
                            ((unsigned long long)k << 32) | (0xFFFFFFFFu - (unsigned)i);
                        if (key < lastk) {
                            unsigned bin = (kmax - k) >> shift;
                            if (bin < BINS - 1) atomicAdd(&hist[bin], 1u);
                        }
                    }
                }
                __syncthreads();
                bin_select(hist, gbuf, &sh_g, &sh_b, &sh_pb, tid, (unsigned)TSEL);
                if (sh_b < BINS - 1) {
                    long long t = (long long)kmax - ((long long)(sh_b + 1) << shift) + 1;
                    thr = (t < 1) ? 1u : (unsigned)t;
                    break;
                }
            }
        }

        if (tid == 0) sh_cnt = 0;
        __syncthreads();
        for (int i = tid; i < NBOX; i += NTH) {
            float s = sraw[(size_t)i * NCLSIN];
            unsigned k = (s > 0.3f) ? fmap(s) : 0u;
            if (k >= thr) {
                unsigned long long key =
                    ((unsigned long long)k << 32) | (0xFFFFFFFFu - (unsigned)i);
                if (key < lastk) {
                    int pos = atomicAdd(&sh_cnt, 1);
                    if (pos < CANDL) cand[pos] = key;
                }
            }
        }
        __syncthreads();
        const int M = sh_cnt < CANDL ? sh_cnt : CANDL;

        sort_desc(cand, M, tid);
        const int PBX = M < CBCAP ? M : CBCAP;
        for (int i = tid; i < PBX; i += NTH) {
            float4 bx = bbase[(int)(0xFFFFFFFFu - (unsigned)cand[i])];
            candbox[i] = bx;
            carea[i] = box_area(bx);
        }
        __syncthreads();
        serial_walk_lds(cand, 0, M, bbase, candbox, carea,
                        selbox, selarea, selscore, nsel, &sh_nsel, tid);
        if (nsel >= MAXSEL || E <= M) break;
        lastk = cand[M - 1];
        __syncthreads();
    }

    if (tid < MAXSEL) {
        bool v = tid < nsel;
        ws_sc[(size_t)bc * MAXSEL + tid] = v ? selscore[tid] : 0.f;
        ((float4*)ws_bx)[(size_t)bc * MAXSEL + tid] =
            v ? selbox[tid] : make_float4(0.f, 0.f, 0.f, 0.f);
    }
}

// ---------------------------------------------------------------------------
// Kernel 2: one block per batch: stable top-200 of 9000 via radix-select+sort.
// Constant KMAX = raw bits of 1.0f (keys are RAW float bits; scores < 1.0
// strictly) folds the E/kmax pass into the histogram pass; shift-retry loop
// preserves exactness. (r18 bug: used fmap(1.0f) -- wrong key space.)
// ---------------------------------------------------------------------------
__global__ __launch_bounds__(NTH) void topk_k(const float* __restrict__ ws_sc,
                                              const float* __restrict__ ws_bx,
                                              float* __restrict__ out_sc,
                                              float* __restrict__ out_bx) {
    __shared__ unsigned hist[BINS];
    __shared__ unsigned gbuf[NTH];
    __shared__ unsigned long long cand[CANDL];
    __shared__ unsigned sh_pb;
    __shared__ int sh_E, sh_g, sh_b, sh_cnt;

    const int tid = threadIdx.x;
    const int b = blockIdx.x;
    const int NF = NCLS * MAXSEL;  // 9000
    const float* sp = ws_sc + (size_t)b * NF;
    const unsigned KMAX = __float_as_uint(1.0f);  // raw-bit space; >= all keys

    unsigned thr = 1u;
    int E = 0;
    for (int shift = 8;; shift += 4) {
        for (int i = tid; i < BINS; i += NTH) hist[i] = 0u;
        __syncthreads();
        unsigned ce = 0;
        for (int f = tid; f < NF; f += NTH) {
            unsigned k = __float_as_uint(sp[f]);
            if (k) {
                ce++;
                unsigned bin = (KMAX - k) >> shift;
                if (bin < BINS - 1) atomicAdd(&hist[bin], 1u);
            }
        }
#pragma unroll
        for (int off = 32; off > 0; off >>= 1)
            ce += (unsigned)__shfl_xor((int)ce, off, 64);
        if ((tid & 63) == 0) gbuf[tid >> 6] = ce;
        __syncthreads();
        if (tid == 0) {
            unsigned c2 = 0;
            for (int w = 0; w < NTH / 64; ++w) c2 += gbuf[w];
            sh_E = (int)c2;
        }
        __syncthreads();
        E = sh_E;
        if (E <= TOPK) { thr = 1u; break; }
        bin_select(hist, gbuf, &sh_g, &sh_b, &sh_pb, tid, (unsigned)TOPK);
        if (sh_b < BINS - 1) {
            long long t = (long long)KMAX - ((long long)(sh_b + 1) << shift) + 1;
            thr = (t < 1) ? 1u : (unsigned)t;
            break;
        }
    }

    if (tid == 0) sh_cnt = 0;
    __syncthreads();
    for (int f = tid; f < NF; f += NTH) {
        unsigned k = __float_as_uint(sp[f]);
        if (k >= thr) {
            int pos = atomicAdd(&sh_cnt, 1);
            if (pos < CANDL)
                cand[pos] = ((unsigned long long)k << 32) | (0xFFFFFFFFu - (unsigned)f);
        }
    }
    __syncthreads();
    int M = sh_cnt < CANDL ? sh_cnt : CANDL;

    if (M < TOPK) {
        int lim = M + TOPK;
        if (lim > NF) lim = NF;
        for (int f = tid; f < lim; f += NTH) {
            unsigned k = __float_as_uint(sp[f]);
            if (k == 0) {
                int pos = atomicAdd(&sh_cnt, 1);
                if (pos < CANDL)
                    cand[pos] = (unsigned long long)(0xFFFFFFFFu - (unsigned)f);
            }
        }
        __syncthreads();
        M = sh_cnt < CANDL ? sh_cnt : CANDL;
    }

    sort_desc(cand, M, tid);

    for (int k = tid; k < TOPK; k += NTH) {
        float cls = 0.f, s = 0.f;
        float4 bx = make_float4(0.f, 0.f, 0.f, 0.f);
        if (k < M) {
            unsigned long long key = cand[k];
            unsigned f = 0xFFFFFFFFu - (unsigned)key;
            s = __uint_as_float((unsigned)(key >> 32));
            cls = (s > 0.f) ? (float)(f / MAXSEL + 1) : 0.f;
            bx = *(const float4*)(ws_bx + ((size_t)b * NF + f) * 4);
        }
        out_sc[((size_t)b * TOPK + k) * 2 + 0] = cls;
        out_sc[((size_t)b * TOPK + k) * 2 + 1] = s;
        ((float4*)out_bx)[(size_t)b * TOPK + k] = bx;
    }
}

// ---------------------------------------------------------------------------
extern "C" void kernel_launch(void* const* d_in, const int* in_sizes, int n_in,
                              void* d_out, int out_size, void* d_ws, size_t ws_size,
                              hipStream_t stream) {
    const float* scores = (const float*)d_in[0];
    const float4* boxes = (const float4*)d_in[1];
    float* out = (float*)d_out;

    const int B = in_sizes[1] / (NBOX * 4);
    const int NBC = B * NCLS;

    // ws layout: cnt2 [NBC * NBLK ints] | cand [NBC*CAP u64] | sc | bx
    size_t off_cand = ((size_t)NBC * NBLK * 4 + 15) & ~(size_t)15;
    size_t off_sc = off_cand + (size_t)NBC * CAP * 8;
    size_t off_bx = off_sc + (size_t)NBC * MAXSEL * 4;
    size_t need = off_bx + (size_t)NBC * MAXSEL * 16;

    char* ws = (char*)d_ws;
    bool use_band = ws_size >= need;

    int* cnt2;
    unsigned long long* cand_g;
    float *ws_sc, *ws_bx;
    if (use_band) {
        cnt2 = (int*)ws;
        cand_g = (unsigned long long*)(ws + off_cand);
        ws_sc = (float*)(ws + off_sc);
        ws_bx = (float*)(ws + off_bx);
    } else {
        cnt2 = (int*)ws;                   // unused
        cand_g = (unsigned long long*)ws;  // unused
        ws_sc = (float*)ws;
        ws_bx = ws_sc + (size_t)NBC * MAXSEL;
    }

    if (use_band) {
        filter_k<<<dim3(NBOX / BOXPB, B), NTH, 0, stream>>>(scores, cand_g, cnt2);
    }
    nms_k<<<dim3(NCLS, B), NTH, 0, stream>>>(cand_g, cnt2, scores, boxes,
                                             ws_sc, ws_bx, use_band ? 1 : 0);
    topk_k<<<B, NTH, 0, stream>>>(ws_sc, ws_bx, out, out + (size_t)B * TOPK * 2);
}

// Round 20
// 93.709 us; speedup vs baseline: 1.5493x; 1.0103x over previous
//
#include <hip/hip_runtime.h>

#define NTH 256
#define NBOX 16384
#define NCLSIN 91
#define NCLS 90
#define MAXSEL 100
#define TOPK 200
#define TSEL 256      // fallback radix-select size
#define CAP 1024      // candidate slice stride per (b,c), in u32 keys
#define CANDL 512     // band capacity (batch walk covers <=256)
#define CBCAP 256     // prefetched candidate boxes
#define NBLK 64       // filter blocks per batch (NBOX / BOXPB)
#define BINS 1024
#define GRP 4         // BINS / NTH
#define T0 0.989f     // band threshold: E[C]=180, sigma 13.4; fallbacks guard
#define BOXPB 256     // boxes per filter block
#define KSL 16        // slot capacity per (class, filter-block)

// order-preserving fp32 <-> u32 (strictly monotone for all non-NaN)
__device__ __forceinline__ unsigned fmap(float f) {
    unsigned u = __float_as_uint(f);
    return (u & 0x80000000u) ? ~u : (u | 0x80000000u);
}
__device__ __forceinline__ float funmap(unsigned u) {
    unsigned b = (u & 0x80000000u) ? (u ^ 0x80000000u) : ~u;
    return __uint_as_float(b);
}
__device__ __forceinline__ unsigned long long shfl_xor_u64(unsigned long long v, int mask) {
    unsigned lo = (unsigned)(v & 0xFFFFFFFFull);
    unsigned hi = (unsigned)(v >> 32);
    lo = __shfl_xor(lo, mask, 64);
    hi = __shfl_xor(hi, mask, 64);
    return ((unsigned long long)hi << 32) | (unsigned long long)lo;
}

// 32-bit band key bijection: scores s in (T0, 1.0) have raw-bit diff < 2^18;
// idx < 2^14. key32 = (diff<<14) | (16383-idx): order == (score desc, idx asc).
#define B0 (__float_as_uint(T0))
__device__ __forceinline__ float key32_score(unsigned k) {
    return __uint_as_float((k >> 14) + B0);
}
__device__ __forceinline__ int key32_idx(unsigned k) {
    return 16383 - (int)(k & 16383u);
}
__device__ __forceinline__ unsigned long long key32_to_64(unsigned k) {
    unsigned bits_s = (k >> 14) + B0;
    int i = 16383 - (int)(k & 16383u);
    return ((unsigned long long)(bits_s | 0x80000000u) << 32) |
           (unsigned long long)(0xFFFFFFFFu - (unsigned)i);
}

// Exact reference IoU>0.5 with division-free fast path (r11, verified exact)
__device__ __forceinline__ bool sup_test(float4 s, float sa, float4 c, float ca) {
    float y1 = fmaxf(s.x, c.x);
    float x1 = fmaxf(s.y, c.y);
    float y2 = fminf(s.z, c.z);
    float x2 = fminf(s.w, c.w);
    float dy = fmaxf(__fsub_rn(y2, y1), 0.f);
    float dx = fmaxf(__fsub_rn(x2, x1), 0.f);
    float inter = __fmul_rn(dy, dx);
    float uni = __fsub_rn(__fadd_rn(sa, ca), inter);
    if (!(uni > 0.f)) return false;
    float t = 0.5f * uni;
    if (inter <= t) return false;
    if (inter > __fmul_rn(t, 1.0000005f)) return true;
    return __fdiv_rn(inter, uni) > 0.5f;
}
__device__ __forceinline__ float box_area(float4 b) {
    return __fmul_rn(__fsub_rn(b.z, b.x), __fsub_rn(b.w, b.y));
}

__device__ __forceinline__ void bin_select(unsigned* hist, unsigned* gbuf,
                                           int* sh_g, int* sh_b, unsigned* sh_pb,
                                           int tid, unsigned need) {
    unsigned gs = 0;
#pragma unroll
    for (int q = 0; q < GRP; ++q) gs += hist[tid * GRP + q];
    gbuf[tid] = gs;
    __syncthreads();
    for (int off = 1; off < NTH; off <<= 1) {
        unsigned add = (tid >= off) ? gbuf[tid - off] : 0u;
        __syncthreads();
        gbuf[tid] += add;
        __syncthreads();
    }
    if (tid == 0) *sh_g = NTH - 1;
    __syncthreads();
    if (gbuf[tid] >= need && (tid == 0 || gbuf[tid - 1] < need)) *sh_g = tid;
    __syncthreads();
    if (tid == 0) {
        int g = *sh_g;
        unsigned acc = (g > 0) ? gbuf[g - 1] : 0u;
        int bs = g * GRP + (GRP - 1);
        unsigned pb = acc;
#pragma unroll
        for (int q = 0; q < GRP; ++q) {
            acc += hist[g * GRP + q];
            if (acc >= need) { bs = g * GRP + q; pb = acc; break; }
            pb = acc;
        }
        *sh_b = bs; *sh_pb = pb;
    }
    __syncthreads();
}

// LDS bitonic sort descending, u64 (fallback for 256 < C <= CANDL and refill)
__device__ __forceinline__ void sort_desc(unsigned long long* cand, int M, int tid) {
    int P = 1;
    while (P < M) P <<= 1;
    for (int i = M + tid; i < P; i += NTH) cand[i] = 0ull;
    __syncthreads();
    for (int kk = 2; kk <= P; kk <<= 1) {
        for (int jj = kk >> 1; jj > 0; jj >>= 1) {
            for (int i = tid; i < P; i += NTH) {
                int ixj = i ^ jj;
                if (ixj > i) {
                    unsigned long long a = cand[i], c = cand[ixj];
                    bool sw = ((i & kk) == 0) ? (a < c) : (a > c);
                    if (sw) { cand[i] = c; cand[ixj] = a; }
                }
            }
            __syncthreads();
        }
    }
}

// ---------------------------------------------------------------------------
// Kernel 0: stream scores once (4x float4/lane). Hits staged as 32-bit band
// keys into per-class LDS slots; counts + entries written to this block's OWN
// slice (no global atomics, no pre-zero). Count > KSL -> exact fallback.
// ---------------------------------------------------------------------------
__global__ __launch_bounds__(NTH) void filter_k(const float* __restrict__ in,
                                                unsigned* __restrict__ cand_g,
                                                int* __restrict__ cnt2) {
    __shared__ int cnt_s[NCLSIN];
    __shared__ unsigned ent[NCLSIN * KSL];  // 5.8 KB (u32 keys)

    const int tid = threadIdx.x;
    const int blkid = blockIdx.x;
    const int n0 = blkid * BOXPB;
    const int b = blockIdx.y;
    const int NF4 = BOXPB * NCLSIN / 4;

    for (int i = tid; i < NCLSIN; i += NTH) cnt_s[i] = 0;
    __syncthreads();

    unsigned long long q0 = 0, q1 = 0, q2 = 0, q3 = 0;
    int lc = 0;

    auto emit = [&](unsigned long long pk) {
        unsigned ee = (unsigned)pk;
        int row = (int)ee / NCLSIN;
        int c = (int)ee - row * NCLSIN;
        if (c == 0) return;  // background
        unsigned i = (unsigned)(n0 + row);
        // key32: (raw-bit diff << 14) | (16383 - i); s > T0 => diff >= 1
        unsigned key = (((unsigned)(pk >> 32) - B0) << 14) | (16383u - i);
        int r = atomicAdd(&cnt_s[c], 1);
        if (r < KSL) ent[c * KSL + r] = key;
    };
    auto proc = [&](float4 v, float mx, int idx4) {
        if (mx > T0) {
            const float sv[4] = {v.x, v.y, v.z, v.w};
#pragma unroll
            for (int qq = 0; qq < 4; ++qq) {
                float s = sv[qq];
                if (s > T0) {
                    unsigned long long pk =
                        ((unsigned long long)__float_as_uint(s) << 32) |
                        (unsigned)(idx4 * 4 + qq);
                    if (lc == 0) q0 = pk;
                    else if (lc == 1) q1 = pk;
                    else if (lc == 2) q2 = pk;
                    else if (lc == 3) q3 = pk;
                    else emit(pk);
                    ++lc;
                }
            }
        }
    };

    const float4 z4 = make_float4(0.f, 0.f, 0.f, 0.f);
    const float4* src = (const float4*)(in + ((size_t)b * NBOX + n0) * NCLSIN);
    for (int i = tid; i < NF4; i += 4 * NTH) {
        int ib = i + NTH, ic = i + 2 * NTH, id = i + 3 * NTH;
        float4 v1 = src[i];
        float4 v2 = (ib < NF4) ? src[ib] : z4;
        float4 v3 = (ic < NF4) ? src[ic] : z4;
        float4 v4 = (id < NF4) ? src[id] : z4;
        float m1 = fmaxf(fmaxf(v1.x, v1.y), fmaxf(v1.z, v1.w));
        float m2 = fmaxf(fmaxf(v2.x, v2.y), fmaxf(v2.z, v2.w));
        float m3 = fmaxf(fmaxf(v3.x, v3.y), fmaxf(v3.z, v3.w));
        float m4 = fmaxf(fmaxf(v4.x, v4.y), fmaxf(v4.z, v4.w));
        if (fmaxf(fmaxf(m1, m2), fmaxf(m3, m4)) > T0) {
            proc(v1, m1, i);
            proc(v2, m2, ib);
            proc(v3, m3, ic);
            proc(v4, m4, id);
        }
    }
    if (lc > 0) emit(q0);
    if (lc > 1) emit(q1);
    if (lc > 2) emit(q2);
    if (lc > 3) emit(q3);
    __syncthreads();

    if (tid >= 1 && tid < NCLSIN) {
        int c = tid;
        int n = cnt_s[c];
        int bc = b * NCLS + c - 1;
        cnt2[(size_t)bc * NBLK + blkid] = n;
        int lim = n < KSL ? n : KSL;
        for (int j = 0; j < lim; ++j)
            cand_g[(size_t)bc * CAP + blkid * KSL + j] = ent[c * KSL + j];
    }
}

// ---------------------------------------------------------------------------
// Serial greedy walk vs LDS-resident selected list (exact; rare paths only).
// ---------------------------------------------------------------------------
__device__ __forceinline__ void serial_walk_lds(
    const unsigned long long* cand, int from, int to,
    const float4* __restrict__ bbase, const float4* candbox, const float* carea,
    float4* selbox, float* selarea, float* selscore,
    int& nsel, int* sh_nsel, int tid) {
    if (tid < 64) {
        for (int m = from; m < to && nsel < MAXSEL; ++m) {
            unsigned long long key = cand[m];
            float4 bx;
            float ca;
            if (m < CBCAP) { bx = candbox[m]; ca = carea[m]; }
            else { bx = bbase[(int)(0xFFFFFFFFu - (unsigned)key)]; ca = box_area(bx); }
            bool sup = false;
            if (tid < nsel) sup = sup_test(selbox[tid], selarea[tid], bx, ca);
            int l2 = tid + 64;
            if (l2 < nsel) sup = sup || sup_test(selbox[l2], selarea[l2], bx, ca);
            if (!__any(sup)) {
                if (tid == 0) {
                    selbox[nsel] = bx;
                    selarea[nsel] = ca;
                    selscore[nsel] = funmap((unsigned)(key >> 32));
                }
                nsel++;
            }
        }
        if (tid == 0) *sh_nsel = nsel;
    }
    __syncthreads();
    nsel = *sh_nsel;
    __syncthreads();
}

// ---------------------------------------------------------------------------
// Kernel 1: one block per (batch, class). r19 structure with 32-bit band keys:
// u32 register bitonic sort (single shfl per exchange), 4-wave supV, wave-0
// ordered intra-batch resolution. Rare C>256 path re-expands to u64. Exact.
// ---------------------------------------------------------------------------
__global__ __launch_bounds__(NTH) void nms_k(
    const unsigned* __restrict__ cand_g,
    const int* __restrict__ cnt2,
    const float* __restrict__ scores_raw,
    const float4* __restrict__ boxes,
    float* __restrict__ ws_sc, float* __restrict__ ws_bx, int use_band) {
    __shared__ unsigned long long cand[CANDL];  // 4 KB (u32 view on fast path)
    __shared__ float4 candbox[CBCAP];           // 4 KB (aliased as hist in fallback)
    __shared__ float carea[CBCAP];              // 1 KB
    __shared__ float4 selbox[MAXSEL];           // 1.6 KB
    __shared__ float selarea[MAXSEL];
    __shared__ float selscore[MAXSEL];
    __shared__ unsigned M32[CBCAP * 2];         // 2 KB: 64-bit intra-batch masks
    __shared__ unsigned long long wballot[4];
    __shared__ int scnt[NBLK];
    __shared__ int spref[NBLK];
    __shared__ unsigned gbuf[NTH];              // 1 KB
    __shared__ unsigned sh_kmax, sh_pb;
    __shared__ int sh_E, sh_g, sh_b, sh_cnt, sh_nsel, sh_C;
    unsigned* hist = (unsigned*)candbox;   // candbox dead while hist live
    unsigned* cand32 = (unsigned*)cand;    // u32 key view (fast path)

    const int tid = threadIdx.x;
    const int wv = tid >> 6, ln = tid & 63;
    const int c0 = blockIdx.x;
    const int b = blockIdx.y;
    const int bc = b * NCLS + c0;
    const float* sraw = scores_raw + (size_t)b * NBOX * NCLSIN + (c0 + 1);
    const float4* bbase = boxes + (size_t)b * NBOX;

    int nsel = 0;
    unsigned long long lastk = ~0ull;

    int C = 0;
    if (use_band) {
        // ---- wave-0 parallel prefix over 64 slot counts ----
        if (tid < 64) {
            int n = cnt2[(size_t)bc * NBLK + tid];
            scnt[tid] = n;
            int x = n;
#pragma unroll
            for (int off = 1; off < 64; off <<= 1) {
                int y = __shfl_up(x, off, 64);
                if (tid >= off) x += y;
            }
            spref[tid] = x - n;  // exclusive prefix
            unsigned long long bb = __ballot(n > KSL);
            if (tid == 63) sh_C = (bb != 0ull) ? -1 : x;  // x@63 = total
        }
        __syncthreads();
        C = sh_C;
        if (C > 0 && C <= CANDL) {
            for (int idx = tid; idx < NBLK * KSL; idx += NTH) {
                int blk = idx >> 4, r = idx & (KSL - 1);
                if (r < scnt[blk])
                    cand32[spref[blk] + r] =
                        cand_g[(size_t)bc * CAP + blk * KSL + r];
            }
            __syncthreads();

            if (C <= 256) {
                // ---- u32 register bitonic sort descending (1 shfl/exchange) ----
                unsigned v = (tid < C) ? cand32[tid] : 0u;
                __syncthreads();
#pragma unroll
                for (int kk = 2; kk <= 256; kk <<= 1) {
#pragma unroll
                    for (int jj = kk >> 1; jj > 0; jj >>= 1) {
                        unsigned o;
                        if (jj >= 64) {  // cross-wave via LDS (3 stages)
                            cand32[tid] = v;
                            __syncthreads();
                            o = cand32[tid ^ jj];
                            __syncthreads();
                        } else {
                            o = (unsigned)__shfl_xor((int)v, jj, 64);
                        }
                        bool lower = (tid & jj) == 0;
                        bool desc = (tid & kk) == 0;
                        v = (lower == desc) ? (v > o ? v : o) : (v < o ? v : o);
                    }
                }
                cand32[tid] = v;
                __syncthreads();

                if (tid < C) {
                    float4 bx = bbase[key32_idx(cand32[tid])];
                    candbox[tid] = bx;
                    carea[tid] = box_area(bx);
                }
                M32[tid] = 0;
                M32[tid + NTH] = 0;
                __syncthreads();

                // ---- intra-batch matrices (r13): pair q -> (i,j), j<i<64 ----
                const int nbatch = (C + 63) >> 6;
                for (int p = tid; p < nbatch * 2016; p += NTH) {
                    int bt = p / 2016;
                    int q = p - bt * 2016;
                    int i = (int)((1.0f + sqrtf(1.0f + 8.0f * (float)q)) * 0.5f);
                    while (i * (i - 1) / 2 > q) --i;
                    while ((i + 1) * i / 2 <= q) ++i;
                    int j = q - i * (i - 1) / 2;
                    int gm = bt * 64 + i, gj = bt * 64 + j;
                    if (gm < C) {
                        if (sup_test(candbox[gj], carea[gj], candbox[gm], carea[gm]))
                            atomicOr(&M32[gm * 2 + (j >> 5)], 1u << (j & 31));
                    }
                }
                __syncthreads();

                // ---- batch walk: 4-wave supV + wave-0 ordered resolution ----
                for (int bt = 0; bt < nbatch; ++bt) {
                    int m = bt * 64 + ln;
                    bool active = m < C;
                    float4 bx = make_float4(0.f, 0.f, 0.f, 0.f);
                    float ca = 0.f;
                    if (active) { bx = candbox[m]; ca = carea[m]; }
                    bool supP = false;
                    if (active) {
                        for (int j = wv; j < nsel; j += 4)
                            supP = supP || sup_test(selbox[j], selarea[j], bx, ca);
                    }
                    unsigned long long bal = __ballot(supP);
                    if (ln == 0) wballot[wv] = bal;
                    __syncthreads();
                    if (tid < 64) {
                        unsigned long long deadSel =
                            wballot[0] | wballot[1] | wballot[2] | wballot[3];
                        unsigned long long actb = __ballot(active);
                        unsigned long long selb = actb & ~deadSel;  // tentative
                        unsigned long long myM = 0ull;
                        if (active)
                            myM = ((unsigned long long)M32[m * 2 + 1] << 32) |
                                  M32[m * 2];
                        unsigned long long U = __ballot(myM != 0ull) & selb;
                        while (U) {
                            int mm = __builtin_ctzll(U);
                            U &= U - 1ull;
                            unsigned long long Mm =
                                ((unsigned long long)M32[(bt * 64 + mm) * 2 + 1] << 32) |
                                M32[(bt * 64 + mm) * 2];
                            unsigned long long below =
                                (mm == 0) ? 0ull : ((1ull << mm) - 1ull);
                            if ((selb >> mm) & 1ull) {
                                if (Mm & selb & below) selb &= ~(1ull << mm);
                            }
                        }
                        int avail = MAXSEL - nsel;
                        int pop = __builtin_popcountll(selb);
                        while (pop > avail) {
                            selb &= ~(1ull << (63 - __builtin_clzll(selb)));
                            --pop;
                        }
                        if ((selb >> ln) & 1ull) {
                            unsigned long long below =
                                (ln == 0) ? 0ull : ((1ull << ln) - 1ull);
                            int pos = nsel + __builtin_popcountll(selb & below);
                            selbox[pos] = bx;
                            selarea[pos] = ca;
                            selscore[pos] = key32_score(cand32[m]);
                        }
                        if (ln == 0) sh_nsel = nsel + pop;
                    }
                    __syncthreads();
                    nsel = sh_nsel;
                    if (nsel >= MAXSEL) break;  // uniform (from shared)
                }
                lastk = key32_to_64(cand32[C - 1]);
                __syncthreads();
            } else {
                // rare (>5 sigma): expand key32 -> key64 (reg-staged), u64 path
                unsigned k0 = (tid < C) ? cand32[tid] : 0u;
                unsigned k1 = (tid + NTH < C) ? cand32[tid + NTH] : 0u;
                __syncthreads();
                if (tid < C) cand[tid] = key32_to_64(k0);
                if (tid + NTH < C) cand[tid + NTH] = key32_to_64(k1);
                __syncthreads();
                sort_desc(cand, C, tid);
                const int PBX = C < CBCAP ? C : CBCAP;
                for (int i = tid; i < PBX; i += NTH) {
                    float4 bx = bbase[(int)(0xFFFFFFFFu - (unsigned)cand[i])];
                    candbox[i] = bx;
                    carea[i] = box_area(bx);
                }
                __syncthreads();
                serial_walk_lds(cand, 0, C, bbase, candbox, carea,
                                selbox, selarea, selscore, nsel, &sh_nsel, tid);
                lastk = cand[C - 1];
            }
        }
    }

    while (nsel < MAXSEL) {
        unsigned km = 0, ce = 0;
        for (int i = tid; i < NBOX; i += NTH) {
            float s = sraw[(size_t)i * NCLSIN];
            unsigned k = (s > 0.3f) ? fmap(s) : 0u;
            if (k) {
                unsigned long long key =
                    ((unsigned long long)k << 32) | (0xFFFFFFFFu - (unsigned)i);
                if (key < lastk) { ce++; km = km > k ? km : k; }
            }
        }
#pragma unroll
        for (int off = 32; off > 0; off >>= 1) {
            unsigned o = (unsigned)__shfl_xor((int)km, off, 64);
            km = km > o ? km : o;
            ce += (unsigned)__shfl_xor((int)ce, off, 64);
        }
        if ((tid & 63) == 0) { gbuf[tid >> 6] = km; gbuf[8 + (tid >> 6)] = ce; }
        __syncthreads();
        if (tid == 0) {
            unsigned m2 = 0, c2 = 0;
            for (int w = 0; w < NTH / 64; ++w) {
                m2 = m2 > gbuf[w] ? m2 : gbuf[w];
                c2 += gbuf[8 + w];
            }
            sh_kmax = m2; sh_E = (int)c2;
        }
        __syncthreads();
        const int E = sh_E;
        const unsigned kmax = sh_kmax;
        if (E == 0) break;

        unsigned thr = 1u;
        if (E > TSEL) {
            for (int shift = 8;; shift += 4) {
                for (int i = tid; i < BINS; i += NTH) hist[i] = 0u;
                __syncthreads();
                for (int i = tid; i < NBOX; i += NTH) {
                    float s = sraw[(size_t)i * NCLSIN];
                    unsigned k = (s > 0.3f) ? fmap(s) : 0u;
                    if (k) {
                        unsigned long long key =
                            ((unsigned long long)k << 32) | (0xFFFFFFFFu - (unsigned)i);
                        if (key < lastk) {
                            unsigned bin = (kmax - k) >> shift;
                            if (bin < BINS - 1) atomicAdd(&hist[bin], 1u);
                        }
                    }
                }
                __syncthreads();
                bin_select(hist, gbuf, &sh_g, &sh_b, &sh_pb, tid, (unsigned)TSEL);
                if (sh_b < BINS - 1) {
                    long long t = (long long)kmax - ((long long)(sh_b + 1) << shift) + 1;
                    thr = (t < 1) ? 1u : (unsigned)t;
                    break;
                }
            }
        }

        if (tid == 0) sh_cnt = 0;
        __syncthreads();
        for (int i = tid; i < NBOX; i += NTH) {
            float s = sraw[(size_t)i * NCLSIN];
            unsigned k = (s > 0.3f) ? fmap(s) : 0u;
            if (k >= thr) {
                unsigned long long key =
                    ((unsigned long long)k << 32) | (0xFFFFFFFFu - (unsigned)i);
                if (key < lastk) {
                    int pos = atomicAdd(&sh_cnt, 1);
                    if (pos < CANDL) cand[pos] = key;
                }
            }
        }
        __syncthreads();
        const int M = sh_cnt < CANDL ? sh_cnt : CANDL;

        sort_desc(cand, M, tid);
        const int PBX = M < CBCAP ? M : CBCAP;
        for (int i = tid; i < PBX; i += NTH) {
            float4 bx = bbase[(int)(0xFFFFFFFFu - (unsigned)cand[i])];
            candbox[i] = bx;
            carea[i] = box_area(bx);
        }
        __syncthreads();
        serial_walk_lds(cand, 0, M, bbase, candbox, carea,
                        selbox, selarea, selscore, nsel, &sh_nsel, tid);
        if (nsel >= MAXSEL || E <= M) break;
        lastk = cand[M - 1];
        __syncthreads();
    }

    if (tid < MAXSEL) {
        bool v = tid < nsel;
        ws_sc[(size_t)bc * MAXSEL + tid] = v ? selscore[tid] : 0.f;
        ((float4*)ws_bx)[(size_t)bc * MAXSEL + tid] =
            v ? selbox[tid] : make_float4(0.f, 0.f, 0.f, 0.f);
    }
}

// ---------------------------------------------------------------------------
// Kernel 2: one block per batch: stable top-200 of 9000 via radix-select+sort.
// Constant KMAX = raw bits of 1.0f (keys are raw float bits; scores < 1.0).
// ---------------------------------------------------------------------------
__global__ __launch_bounds__(NTH) void topk_k(const float* __restrict__ ws_sc,
                                              const float* __restrict__ ws_bx,
                                              float* __restrict__ out_sc,
                                              float* __restrict__ out_bx) {
    __shared__ unsigned hist[BINS];
    __shared__ unsigned gbuf[NTH];
    __shared__ unsigned long long cand[CANDL];
    __shared__ unsigned sh_pb;
    __shared__ int sh_E, sh_g, sh_b, sh_cnt;

    const int tid = threadIdx.x;
    const int b = blockIdx.x;
    const int NF = NCLS * MAXSEL;  // 9000
    const float* sp = ws_sc + (size_t)b * NF;
    const unsigned KMAX = __float_as_uint(1.0f);

    unsigned thr = 1u;
    int E = 0;
    for (int shift = 8;; shift += 4) {
        for (int i = tid; i < BINS; i += NTH) hist[i] = 0u;
        __syncthreads();
        unsigned ce = 0;
        for (int f = tid; f < NF; f += NTH) {
            unsigned k = __float_as_uint(sp[f]);
            if (k) {
                ce++;
                unsigned bin = (KMAX - k) >> shift;
                if (bin < BINS - 1) atomicAdd(&hist[bin], 1u);
            }
        }
#pragma unroll
        for (int off = 32; off > 0; off >>= 1)
            ce += (unsigned)__shfl_xor((int)ce, off, 64);
        if ((tid & 63) == 0) gbuf[tid >> 6] = ce;
        __syncthreads();
        if (tid == 0) {
            unsigned c2 = 0;
            for (int w = 0; w < NTH / 64; ++w) c2 += gbuf[w];
            sh_E = (int)c2;
        }
        __syncthreads();
        E = sh_E;
        if (E <= TOPK) { thr = 1u; break; }
        bin_select(hist, gbuf, &sh_g, &sh_b, &sh_pb, tid, (unsigned)TOPK);
        if (sh_b < BINS - 1) {
            long long t = (long long)KMAX - ((long long)(sh_b + 1) << shift) + 1;
            thr = (t < 1) ? 1u : (unsigned)t;
            break;
        }
    }

    if (tid == 0) sh_cnt = 0;
    __syncthreads();
    for (int f = tid; f < NF; f += NTH) {
        unsigned k = __float_as_uint(sp[f]);
        if (k >= thr) {
            int pos = atomicAdd(&sh_cnt, 1);
            if (pos < CANDL)
                cand[pos] = ((unsigned long long)k << 32) | (0xFFFFFFFFu - (unsigned)f);
        }
    }
    __syncthreads();
    int M = sh_cnt < CANDL ? sh_cnt : CANDL;

    if (M < TOPK) {
        int lim = M + TOPK;
        if (lim > NF) lim = NF;
        for (int f = tid; f < lim; f += NTH) {
            unsigned k = __float_as_uint(sp[f]);
            if (k == 0) {
                int pos = atomicAdd(&sh_cnt, 1);
                if (pos < CANDL)
                    cand[pos] = (unsigned long long)(0xFFFFFFFFu - (unsigned)f);
            }
        }
        __syncthreads();
        M = sh_cnt < CANDL ? sh_cnt : CANDL;
    }

    sort_desc(cand, M, tid);

    for (int k = tid; k < TOPK; k += NTH) {
        float cls = 0.f, s = 0.f;
        float4 bx = make_float4(0.f, 0.f, 0.f, 0.f);
        if (k < M) {
            unsigned long long key = cand[k];
            unsigned f = 0xFFFFFFFFu - (unsigned)key;
            s = __uint_as_float((unsigned)(key >> 32));
            cls = (s > 0.f) ? (float)(f / MAXSEL + 1) : 0.f;
            bx = *(const float4*)(ws_bx + ((size_t)b * NF + f) * 4);
        }
        out_sc[((size_t)b * TOPK + k) * 2 + 0] = cls;
        out_sc[((size_t)b * TOPK + k) * 2 + 1] = s;
        ((float4*)out_bx)[(size_t)b * TOPK + k] = bx;
    }
}

// ---------------------------------------------------------------------------
extern "C" void kernel_launch(void* const* d_in, const int* in_sizes, int n_in,
                              void* d_out, int out_size, void* d_ws, size_t ws_size,
                              hipStream_t stream) {
    const float* scores = (const float*)d_in[0];
    const float4* boxes = (const float4*)d_in[1];
    float* out = (float*)d_out;

    const int B = in_sizes[1] / (NBOX * 4);
    const int NBC = B * NCLS;

    // ws layout: cnt2 [NBC * NBLK ints] | cand [NBC*CAP u32] | sc | bx
    size_t off_cand = ((size_t)NBC * NBLK * 4 + 15) & ~(size_t)15;
    size_t off_sc = off_cand + (size_t)NBC * CAP * 4;
    size_t off_bx = off_sc + (size_t)NBC * MAXSEL * 4;
    size_t need = off_bx + (size_t)NBC * MAXSEL * 16;

    char* ws = (char*)d_ws;
    bool use_band = ws_size >= need;

    int* cnt2;
    unsigned* cand_g;
    float *ws_sc, *ws_bx;
    if (use_band) {
        cnt2 = (int*)ws;
        cand_g = (unsigned*)(ws + off_cand);
        ws_sc = (float*)(ws + off_sc);
        ws_bx = (float*)(ws + off_bx);
    } else {
        cnt2 = (int*)ws;          // unused
        cand_g = (unsigned*)ws;   // unused
        ws_sc = (float*)ws;
        ws_bx = ws_sc + (size_t)NBC * MAXSEL;
    }

    if (use_band) {
        filter_k<<<dim3(NBOX / BOXPB, B), NTH, 0, stream>>>(scores, cand_g, cnt2);
    }
    nms_k<<<dim3(NCLS, B), NTH, 0, stream>>>(cand_g, cnt2, scores, boxes,
                                             ws_sc, ws_bx, use_band ? 1 : 0);
    topk_k<<<B, NTH, 0, stream>>>(ws_sc, ws_bx, out, out + (size_t)B * TOPK * 2);
}